// Round 1
// 1215.638 us; speedup vs baseline: 1.1492x; 1.1492x over previous
//
#include <hip/hip_runtime.h>
#include <cstdint>

#define HID  4096
#define NHD  16
#define HDIM 256
#define SEQ  1024
#define BB   4
#define N3   12288
#define TOK  4096

typedef unsigned short u16;
typedef __bf16 bf16x8 __attribute__((ext_vector_type(8)));
typedef float  f32x4  __attribute__((ext_vector_type(4)));
typedef float  f32x16 __attribute__((ext_vector_type(16)));

__device__ __forceinline__ u16 f2b(float f) {
    unsigned u = __builtin_bit_cast(unsigned, f);
    u += 0x7fffu + ((u >> 16) & 1u);          // RNE
    return (u16)(u >> 16);
}
__device__ __forceinline__ float b2f(u16 v) {
    unsigned u = ((unsigned)v) << 16;
    return __builtin_bit_cast(float, u);
}

typedef __attribute__((address_space(3))) unsigned       lds_u32;
typedef const __attribute__((address_space(1))) unsigned glb_u32;
__device__ __forceinline__ void async16(const void* g, void* l) {
    __builtin_amdgcn_global_load_lds((glb_u32*)g, (lds_u32*)l, 16, 0, 0);
}

// ---------------- cast fp32 -> bf16 (row-major) ----------------
__global__ __launch_bounds__(256) void cast_bf16(const float4* __restrict__ in,
                                                 uint4* __restrict__ out, int n8) {
    int i = blockIdx.x * 256 + threadIdx.x;
    if (i >= n8) return;
    float4 a = in[2 * i], b = in[2 * i + 1];
    union { u16 h[8]; uint4 v; } o;
    o.h[0] = f2b(a.x); o.h[1] = f2b(a.y); o.h[2] = f2b(a.z); o.h[3] = f2b(a.w);
    o.h[4] = f2b(b.x); o.h[5] = f2b(b.y); o.h[6] = f2b(b.z); o.h[7] = f2b(b.w);
    out[i] = o.v;
}

// ---------------- transpose-cast: in[R][C] fp32 -> out[C][R] bf16 ----------------
__global__ __launch_bounds__(256) void tcast(const float* __restrict__ in,
                                             u16* __restrict__ out, int R, int C) {
    __shared__ u16 sT[64 * 80];
    const int c0 = blockIdx.x * 64, r0 = blockIdx.y * 64;
    const int t = threadIdx.x;
    const int rr = t >> 4, cc = (t & 15) * 4;
    for (int rnd = 0; rnd < 4; rnd++) {
        int r = rnd * 16 + rr;
        float4 v = *(const float4*)(in + (size_t)(r0 + r) * C + c0 + cc);
        sT[(cc + 0) * 80 + r] = f2b(v.x);
        sT[(cc + 1) * 80 + r] = f2b(v.y);
        sT[(cc + 2) * 80 + r] = f2b(v.z);
        sT[(cc + 3) * 80 + r] = f2b(v.w);
    }
    __syncthreads();
    const int orow = t >> 2, oc = (t & 3) * 16;
    u16* dst = out + (size_t)(c0 + orow) * R + r0 + oc;
    *(uint4*)dst       = *(uint4*)&sT[orow * 80 + oc];
    *(uint4*)(dst + 8) = *(uint4*)&sT[orow * 80 + oc + 8];
}

// ---------------- bf16 GEMM: C[M][N] = A[M][K] * Bt[N][K]^T ----------------
// 256x256 tile, BK=64, 512 threads = 8 waves (2M x 4N), 16x16x32 MFMA.
// LDS: 2 double-buffers x (A,B) x 2 k-slices of [256 rows][32 k] bf16 = 128 KiB.
// 16B chunks XOR-swizzled by (row&3) -- applied on the GLOBAL source side so the
// linear global_load_lds dest stays valid; ds_read applies the same XOR.
// 4 phases per K-tile: {ds_read 8|4 frags, stage 1 k-slice (2x gload_lds),
//  raw s_barrier, lgkmcnt(0), setprio(1), 16 MFMA, setprio(0), barrier}.
// Counted vmcnt(4) publish at end of P1/P3 only (never vmcnt(0) in main loop).
template <bool OUT_BF16>
__global__ __launch_bounds__(512, 2) void gemm256(const u16* __restrict__ A,
                                                  const u16* __restrict__ Bt,
                                                  void* __restrict__ Cout,
                                                  int M, int N, int K) {
    __shared__ alignas(16) u16 lds[65536];   // 128 KiB
    const int t = threadIdx.x;
    const int lane = t & 63, w = t >> 6;
    const int wm = w >> 2, wn = w & 3;
    const int fm = lane & 15, g = lane >> 4;

    // XCD-aware block swizzle (grid is 1-D, nwg % 8 == 0 for our shapes)
    const int nwg = (int)gridDim.x;
    const int cpx = nwg >> 3;
    const int swz = (((int)blockIdx.x) & 7) * cpx + (((int)blockIdx.x) >> 3);
    const int gm = M >> 8;
    const int mblk = swz % gm, nblk = swz / gm;
    const int m0 = mblk << 8, n0 = nblk << 8;

    // staging source (per-thread): row = t>>2 (+128 for 2nd issue), 16B chunk
    // pre-swizzled so linear LDS slot (row, c) holds global chunk c ^ (row&3)
    const int srow = t >> 2;
    const int schk = ((t & 3) ^ (srow & 3)) * 8;
    const u16* gA = A  + (size_t)(m0 + srow) * K + schk;
    const u16* gB = Bt + (size_t)(n0 + srow) * K + schk;
    const size_t hstep = (size_t)128 * K;
    const int ldst = t * 8;

    // fragment read offsets (elems): slice is [256][32], chunk = g ^ (row&3)
    const int cxor = (g ^ (fm & 3)) * 8;
    const int aoff = (wm * 128 + fm) * 32 + cxor;            // A region at 0
    const int boff = 16384 + (wn * 64 + fm) * 32 + cxor;     // B region at +16384

    f32x4 acc[8][4];
#pragma unroll
    for (int i = 0; i < 8; i++)
#pragma unroll
        for (int j = 0; j < 4; j++) acc[i][j] = f32x4{0.f, 0.f, 0.f, 0.f};

    const int nk = K >> 6;

#define STG_A(BO, KT, KS) do { \
    const u16* s_ = gA + (size_t)(KT) * 64 + (KS) * 32; \
    async16(s_,         &lds[(BO) + (KS) * 8192 + ldst]); \
    async16(s_ + hstep, &lds[(BO) + (KS) * 8192 + 4096 + ldst]); } while (0)
#define STG_B(BO, KT, KS) do { \
    const u16* s_ = gB + (size_t)(KT) * 64 + (KS) * 32; \
    async16(s_,         &lds[(BO) + 16384 + (KS) * 8192 + ldst]); \
    async16(s_ + hstep, &lds[(BO) + 16384 + (KS) * 8192 + 4096 + ldst]); } while (0)

    bf16x8 a0[4], a1[4], bfr[4];

#define LD_A0(BO, KS) { _Pragma("unroll") for (int m_ = 0; m_ < 4; m_++) \
    a0[m_] = *(const bf16x8*)&lds[(BO) + (KS) * 8192 + aoff + m_ * 512]; }
#define LD_A1(BO, KS) { _Pragma("unroll") for (int m_ = 0; m_ < 4; m_++) \
    a1[m_] = *(const bf16x8*)&lds[(BO) + (KS) * 8192 + 2048 + aoff + m_ * 512]; }
#define LD_B(BO, KS) { _Pragma("unroll") for (int n_ = 0; n_ < 4; n_++) \
    bfr[n_] = *(const bf16x8*)&lds[(BO) + (KS) * 8192 + boff + n_ * 512]; }
#define MM(AR, MO) { _Pragma("unroll") for (int m_ = 0; m_ < 4; m_++) \
    _Pragma("unroll") for (int n_ = 0; n_ < 4; n_++) \
    acc[(MO) + m_][n_] = __builtin_amdgcn_mfma_f32_16x16x32_bf16(AR[m_], bfr[n_], acc[(MO) + m_][n_], 0, 0, 0); }
#define BARX __builtin_amdgcn_s_barrier()
#define LGKM0 asm volatile("s_waitcnt lgkmcnt(0)" ::: "memory")
#define VM(N_) asm volatile("s_waitcnt vmcnt(" #N_ ")" ::: "memory")
#define PHASE_MID BARX; LGKM0; __builtin_amdgcn_s_setprio(1)
#define PHASE_END __builtin_amdgcn_s_setprio(0); BARX

    // prologue: stage tile 0 (Aks0, Bks0, Aks1, Bks1), publish Aks0+Bks0
    STG_A(0, 0, 0); STG_B(0, 0, 0); STG_A(0, 0, 1); STG_B(0, 0, 1);
    VM(4); BARX;

#pragma unroll 1
    for (int kt = 0; kt < nk - 1; kt++) {
        const int bo = (kt & 1) << 15, nb = bo ^ 32768;
        // P0: frags m0-3,ks0 + B ks0 | stage next Aks0
        LD_A0(bo, 0); LD_B(bo, 0);
        STG_A(nb, kt + 1, 0);
        PHASE_MID; MM(a0, 0); PHASE_END;
        // P1: frags m4-7,ks0 | stage next Bks0 | publish this tile's ks1 slices
        LD_A1(bo, 0);
        STG_B(nb, kt + 1, 0);
        VM(4);
        PHASE_MID; MM(a1, 4); PHASE_END;
        // P2: frags m0-3,ks1 + B ks1 | stage next Aks1
        LD_A0(bo, 1); LD_B(bo, 1);
        STG_A(nb, kt + 1, 1);
        PHASE_MID; MM(a0, 0); PHASE_END;
        // P3: frags m4-7,ks1 | stage next Bks1 | publish next tile's ks0 slices
        LD_A1(bo, 1);
        STG_B(nb, kt + 1, 1);
        VM(4);
        PHASE_MID; MM(a1, 4); PHASE_END;
    }
    {   // tail tile: no staging, drain counts 4 -> 0
        const int bo = ((nk - 1) & 1) << 15;
        LD_A0(bo, 0); LD_B(bo, 0);
        PHASE_MID; MM(a0, 0); PHASE_END;
        LD_A1(bo, 0);
        VM(0);
        PHASE_MID; MM(a1, 4); PHASE_END;
        LD_A0(bo, 1); LD_B(bo, 1);
        PHASE_MID; MM(a0, 0); PHASE_END;
        LD_A1(bo, 1);
        PHASE_MID; MM(a1, 4); PHASE_END;
    }

    // C/D layout (16x16): col = lane&15, row = (lane>>4)*4 + reg
    const int crow0 = m0 + wm * 128 + g * 4;
    const int ccol = n0 + wn * 64 + fm;
#pragma unroll
    for (int mi = 0; mi < 8; mi++)
#pragma unroll
        for (int r = 0; r < 4; r++) {
            const size_t row = (size_t)(crow0 + mi * 16 + r);
            if (OUT_BF16) {
                u16* p = (u16*)Cout + row * N + ccol;
#pragma unroll
                for (int n_ = 0; n_ < 4; n_++) p[n_ * 16] = f2b(acc[mi][n_][r]);
            } else {
                float* p = (float*)Cout + row * N + ccol;
#pragma unroll
                for (int n_ = 0; n_ < 4; n_++) p[n_ * 16] = acc[mi][n_][r];
            }
        }
#undef STG_A
#undef STG_B
#undef LD_A0
#undef LD_A1
#undef LD_B
#undef MM
#undef BARX
#undef LGKM0
#undef VM
#undef PHASE_MID
#undef PHASE_END
}

// ---------------- RoPE + relayout ----------------
// qkv bf16 [tok][12288] -> Q,K [b][h][s][256] bf16 (rope applied), VT [b][h][256][s] bf16
__global__ __launch_bounds__(256) void rope_relayout(const int* __restrict__ pos_ids,
                                                     const u16* __restrict__ qkv,
                                                     u16* __restrict__ Qo,
                                                     u16* __restrict__ Ko,
                                                     u16* __restrict__ VTo) {
    __shared__ u16 sV[64 * 256];
    const int st = blockIdx.x, h = blockIdx.y, b = blockIdx.z;
    const int t = threadIdx.x;
    const int sbase = st * 64;

    {
        const u16* vbase = qkv + (size_t)(b * SEQ + sbase) * N3 + 2 * HID + h * HDIM;
        const int dcol = (t & 31) * 8;
        const int tokoff = t >> 5;
#pragma unroll
        for (int r = 0; r < 4; r++)
#pragma unroll
            for (int s8 = 0; s8 < 8; s8++) {
                int tok = r * 16 + s8 * 2 + tokoff;
                async16(vbase + (size_t)tok * N3 + dcol, &sV[r * 4096 + s8 * 512 + t * 8]);
            }
    }

    const int tok = t & 63, part = t >> 6;
    const int s = sbase + tok;
    const int pos = pos_ids[b * SEQ + s];
    const int isK = part >> 1, isPass = part & 1;
    const u16* src = qkv + (size_t)(b * SEQ + s) * N3 + isK * HID + h * HDIM + isPass * 128;
    u16* dst = (isK ? Ko : Qo) + ((size_t)((b * NHD + h) * SEQ + s)) * HDIM + isPass * 128;
    if (!isPass) {
        const float fpos = (float)pos;
#pragma unroll
        for (int c = 0; c < 8; c++) {
            bf16x8 xa = *(const bf16x8*)(src + c * 8);
            bf16x8 xb = *(const bf16x8*)(src + 64 + c * 8);
            union { u16 h[8]; uint4 v; } o1, o2;
#pragma unroll
            for (int j = 0; j < 8; j++) {
                int i = c * 8 + j;
                float invf = __expf((float)i * -0.14391156831212787f);
                float ang = fpos * invf;
                float sn, cs;
                __sincosf(ang, &sn, &cs);
                float x1 = (float)xa[j], x2 = (float)xb[j];
                o1.h[j] = f2b(x1 * cs - x2 * sn);
                o2.h[j] = f2b(x2 * cs + x1 * sn);
            }
            *(uint4*)(dst + c * 8)      = o1.v;
            *(uint4*)(dst + 64 + c * 8) = o2.v;
        }
    } else {
        const uint4* s4 = (const uint4*)src;
        uint4* d4 = (uint4*)dst;
#pragma unroll
        for (int c = 0; c < 16; c++) d4[c] = s4[c];
    }

    asm volatile("s_waitcnt vmcnt(0)" ::: "memory");
    __syncthreads();

    u16* vt = VTo + ((size_t)((b * NHD + h) * HDIM + t)) * SEQ + sbase;
#pragma unroll
    for (int g = 0; g < 8; g++) {
        union { u16 h[8]; uint4 v; } o;
#pragma unroll
        for (int j = 0; j < 8; j++) o.h[j] = sV[(g * 8 + j) * 256 + t];
        *(uint4*)(vt + g * 8) = o.v;
    }
}

// ---------------- flash attention (causal), per (b,h,64-row q-tile) ----------------
// sK [32 key][256 d] with column-chunks xor-swizzled by (key&7);
// sVT [256 d][32 s] with s-chunks xor-swizzled by (d&3).
__global__ __launch_bounds__(256) void attn_fwd(const u16* __restrict__ Q,
                                                const u16* __restrict__ K,
                                                const u16* __restrict__ VT,
                                                u16* __restrict__ attnO) {
    __shared__ u16 sK[32 * 256];
    __shared__ u16 sVT[256 * 32];
    __shared__ u16 sP[4 * 16 * 32];
    const int qt = (int)gridDim.x - 1 - (int)blockIdx.x;  // heavy tiles first
    const int h = blockIdx.y, b = blockIdx.z;
    const int t = threadIdx.x, lane = t & 63, w = t >> 6;
    const int fm = lane & 15, g = lane >> 4, fk = g * 8;
    const int qbase = qt * 64;
    const size_t head = ((size_t)(b * NHD + h)) * SEQ * HDIM;
    const u16* qptr = Q + head + (size_t)(qbase + w * 16 + fm) * HDIM;
    bf16x8 qf[8];
#pragma unroll
    for (int kk = 0; kk < 8; kk++) qf[kk] = *(const bf16x8*)(qptr + kk * 32 + fk);
    const f32x4 z = {0.f, 0.f, 0.f, 0.f};
    f32x4 O[16];
#pragma unroll
    for (int n = 0; n < 16; n++) O[n] = z;
    float mrow[4] = {-1e30f, -1e30f, -1e30f, -1e30f};
    float lrow[4] = {0.f, 0.f, 0.f, 0.f};
    const int nkt = qt * 2 + 2;
    const u16* kbaseP = K + head;
    const u16* vtbase = VT + head;
    const int qg_base = qbase + w * 16 + g * 4;

    for (int kb = 0; kb < nkt; kb++) {
        {
            const int krow = t >> 5;                            // key row within 8
            const int dcol = ((t & 31) ^ krow) * 8;             // swizzle by key&7
#pragma unroll
            for (int r = 0; r < 4; r++)
                async16(kbaseP + (size_t)(kb * 32 + r * 8 + krow) * HDIM + dcol,
                        &sK[r * 2048 + t * 8]);
            const int drow = t >> 2;
            const int scol = (((t & 3) ^ (drow & 3))) * 8;      // swizzle by d&3
#pragma unroll
            for (int r = 0; r < 4; r++)
                async16(vtbase + (size_t)(r * 64 + drow) * SEQ + kb * 32 + scol,
                        &sVT[r * 2048 + t * 8]);
        }
        asm volatile("s_waitcnt vmcnt(0)" ::: "memory");
        __syncthreads();

        f32x4 sc0 = z, sc1 = z;
#pragma unroll
        for (int kk = 0; kk < 8; kk++) {
            const int p = ((kk * 4 + g) ^ (fm & 7)) * 8;
            bf16x8 kf0 = *(const bf16x8*)&sK[fm * 256 + p];
            bf16x8 kf1 = *(const bf16x8*)&sK[(16 + fm) * 256 + p];
            sc0 = __builtin_amdgcn_mfma_f32_16x16x32_bf16(qf[kk], kf0, sc0, 0, 0, 0);
            sc1 = __builtin_amdgcn_mfma_f32_16x16x32_bf16(qf[kk], kf1, sc1, 0, 0, 0);
        }
        const int kg0 = kb * 32 + fm, kg1 = kg0 + 16;
        float alpha[4];
#pragma unroll
        for (int j = 0; j < 4; j++) {
            const int qg = qg_base + j;
            float s0 = (kg0 <= qg) ? sc0[j] * 0.0625f : -1e30f;
            float s1 = (kg1 <= qg) ? sc1[j] * 0.0625f : -1e30f;
            float mx = fmaxf(s0, s1);
            mx = fmaxf(mx, __shfl_xor(mx, 1, 64));
            mx = fmaxf(mx, __shfl_xor(mx, 2, 64));
            mx = fmaxf(mx, __shfl_xor(mx, 4, 64));
            mx = fmaxf(mx, __shfl_xor(mx, 8, 64));
            const float mn = fmaxf(mrow[j], mx);
            alpha[j] = __expf(mrow[j] - mn);
            mrow[j] = mn;
            float p0 = __expf(s0 - mn);
            float p1 = __expf(s1 - mn);
            float rs = p0 + p1;
            rs += __shfl_xor(rs, 1, 64);
            rs += __shfl_xor(rs, 2, 64);
            rs += __shfl_xor(rs, 4, 64);
            rs += __shfl_xor(rs, 8, 64);
            lrow[j] = lrow[j] * alpha[j] + rs;
            const int r = g * 4 + j;
            sP[w * 512 + r * 32 + fm]      = f2b(p0);
            sP[w * 512 + r * 32 + 16 + fm] = f2b(p1);
        }
#pragma unroll
        for (int n = 0; n < 16; n++) {
            O[n][0] *= alpha[0]; O[n][1] *= alpha[1];
            O[n][2] *= alpha[2]; O[n][3] *= alpha[3];
        }
        bf16x8 pf = *(const bf16x8*)&sP[w * 512 + fm * 32 + fk];
#pragma unroll
        for (int n = 0; n < 16; n++) {
            const int d = n * 16 + fm;
            bf16x8 vf = *(const bf16x8*)&sVT[d * 32 + ((g ^ (fm & 3)) << 3)];
            O[n] = __builtin_amdgcn_mfma_f32_16x16x32_bf16(pf, vf, O[n], 0, 0, 0);
        }
        __syncthreads();
    }
#pragma unroll
    for (int j = 0; j < 4; j++) {
        const int r = g * 4 + j;
        const float inv = 1.0f / lrow[j];
        u16* orow = attnO + (size_t)(b * SEQ + qbase + w * 16 + r) * HID + h * HDIM;
#pragma unroll
        for (int n = 0; n < 16; n++)
            orow[n * 16 + fm] = f2b(O[n][j] * inv);
    }
}

// ---------------- launch ----------------
extern "C" void kernel_launch(void* const* d_in, const int* in_sizes, int n_in,
                              void* d_out, int out_size, void* d_ws, size_t ws_size,
                              hipStream_t stream) {
    (void)in_sizes; (void)n_in; (void)out_size; (void)ws_size;
    const int*   pos    = (const int*)d_in[0];
    const float* hidden = (const float*)d_in[1];
    const float* wqkv   = (const float*)d_in[2];
    const float* wout   = (const float*)d_in[3];
    float* out = (float*)d_out;
    char* ws = (char*)d_ws;

    u16* hiddenB = (u16*)ws;                              //  33,554,432 B
    u16* wqkvT   = (u16*)(ws + (size_t)33554432);         // 100,663,296 B
    u16* woutT   = (u16*)(ws + (size_t)134217728);        //  33,554,432 B
    u16* qkv     = (u16*)(ws + (size_t)167772160);        // 100,663,296 B
    u16* Qb    = wqkvT;                 // after GEMM1, wqkvT is dead
    u16* Kb    = wqkvT + 16777216;
    u16* VTb   = wqkvT + 33554432;
    u16* attnB = qkv;                   // after rope, qkv is dead

    cast_bf16<<<dim3(TOK * HID / 8 / 256), 256, 0, stream>>>(
        (const float4*)hidden, (uint4*)hiddenB, TOK * HID / 8);
    tcast<<<dim3(N3 / 64, HID / 64), 256, 0, stream>>>(wqkv, wqkvT, HID, N3);
    tcast<<<dim3(HID / 64, HID / 64), 256, 0, stream>>>(wout, woutT, HID, HID);
    gemm256<true><<<dim3((TOK / 256) * (N3 / 256)), 512, 0, stream>>>(
        hiddenB, wqkvT, qkv, TOK, N3, HID);
    rope_relayout<<<dim3(SEQ / 64, NHD, BB), 256, 0, stream>>>(pos, qkv, Qb, Kb, VTb);
    attn_fwd<<<dim3(SEQ / 64, NHD, BB), 256, 0, stream>>>(Qb, Kb, VTb, attnB);
    gemm256<false><<<dim3((TOK / 256) * (HID / 256)), 512, 0, stream>>>(
        attnB, woutT, out, TOK, HID, HID);
}

// Round 2
// 1210.022 us; speedup vs baseline: 1.1545x; 1.0046x over previous
//
#include <hip/hip_runtime.h>
#include <cstdint>

#define HID  4096
#define NHD  16
#define HDIM 256
#define SEQ  1024
#define BB   4
#define N3   12288
#define TOK  4096

typedef unsigned short u16;
typedef __bf16 bf16x8 __attribute__((ext_vector_type(8)));
typedef float  f32x4  __attribute__((ext_vector_type(4)));
typedef float  f32x16 __attribute__((ext_vector_type(16)));

__device__ __forceinline__ u16 f2b(float f) {
    unsigned u = __builtin_bit_cast(unsigned, f);
    u += 0x7fffu + ((u >> 16) & 1u);          // RNE
    return (u16)(u >> 16);
}
__device__ __forceinline__ float b2f(u16 v) {
    unsigned u = ((unsigned)v) << 16;
    return __builtin_bit_cast(float, u);
}

typedef __attribute__((address_space(3))) unsigned       lds_u32;
typedef const __attribute__((address_space(1))) unsigned glb_u32;
__device__ __forceinline__ void async16(const void* g, void* l) {
    __builtin_amdgcn_global_load_lds((glb_u32*)g, (lds_u32*)l, 16, 0, 0);
}

// ---------------- cast fp32 -> bf16 (row-major) ----------------
__global__ __launch_bounds__(256) void cast_bf16(const float4* __restrict__ in,
                                                 uint4* __restrict__ out, int n8) {
    int i = blockIdx.x * 256 + threadIdx.x;
    if (i >= n8) return;
    float4 a = in[2 * i], b = in[2 * i + 1];
    union { u16 h[8]; uint4 v; } o;
    o.h[0] = f2b(a.x); o.h[1] = f2b(a.y); o.h[2] = f2b(a.z); o.h[3] = f2b(a.w);
    o.h[4] = f2b(b.x); o.h[5] = f2b(b.y); o.h[6] = f2b(b.z); o.h[7] = f2b(b.w);
    out[i] = o.v;
}

// ---------------- transpose-cast: in[R][C] fp32 -> out[C][R] bf16 ----------------
__global__ __launch_bounds__(256) void tcast(const float* __restrict__ in,
                                             u16* __restrict__ out, int R, int C) {
    __shared__ u16 sT[64 * 80];
    const int c0 = blockIdx.x * 64, r0 = blockIdx.y * 64;
    const int t = threadIdx.x;
    const int rr = t >> 4, cc = (t & 15) * 4;
    for (int rnd = 0; rnd < 4; rnd++) {
        int r = rnd * 16 + rr;
        float4 v = *(const float4*)(in + (size_t)(r0 + r) * C + c0 + cc);
        sT[(cc + 0) * 80 + r] = f2b(v.x);
        sT[(cc + 1) * 80 + r] = f2b(v.y);
        sT[(cc + 2) * 80 + r] = f2b(v.z);
        sT[(cc + 3) * 80 + r] = f2b(v.w);
    }
    __syncthreads();
    const int orow = t >> 2, oc = (t & 3) * 16;
    u16* dst = out + (size_t)(c0 + orow) * R + r0 + oc;
    *(uint4*)dst       = *(uint4*)&sT[orow * 80 + oc];
    *(uint4*)(dst + 8) = *(uint4*)&sT[orow * 80 + oc + 8];
}

// ---------------- bf16 GEMM: C[M][N] = A[M][K] * Bt[N][K]^T ----------------
// 256x256 tile, BK=64, 512 threads = 8 waves (2M x 4N), 16x16x32 MFMA.
// LDS: 2 double-buffers x (A,B) x 2 k-slices of [256 rows][32 k] bf16 = 128 KiB.
// Chunk swizzle: swz(row) = (row&3) ^ ((row>>2)&2).  The (row>>2)&2 term XORs
// row BIT 3 into chunk bit 1 -- the 512B-alias bit for ds_read_b128's 16B-slot
// conflict axis (32 slots x 16B = 512B span; 64B rows alias at row+8).  With it,
// widebank(fm) = (fm*4 + (g^swz(fm))) mod 32 is a bijection over the 16 lanes
// of each quarter-wave -> conflict-free fragment reads (m201's st_16x32 insight).
// Applied on the GLOBAL source side (global_load_lds dest stays linear); ds_read
// applies the same involution.
// 4 phases per K-tile: {ds_read 8|4 frags, stage 1 k-slice (2x gload_lds),
//  raw s_barrier, lgkmcnt(0), setprio(1), 16 MFMA, setprio(0), barrier}.
// Counted vmcnt(4) publish at end of P1/P3 only (never vmcnt(0) in main loop).
template <bool OUT_BF16>
__global__ __launch_bounds__(512, 2) void gemm256(const u16* __restrict__ A,
                                                  const u16* __restrict__ Bt,
                                                  void* __restrict__ Cout,
                                                  int M, int N, int K) {
    __shared__ alignas(16) u16 lds[65536];   // 128 KiB
    const int t = threadIdx.x;
    const int lane = t & 63, w = t >> 6;
    const int wm = w >> 2, wn = w & 3;
    const int fm = lane & 15, g = lane >> 4;

    // XCD-aware block swizzle (grid is 1-D, nwg % 8 == 0 for our shapes)
    const int nwg = (int)gridDim.x;
    const int cpx = nwg >> 3;
    const int swz = (((int)blockIdx.x) & 7) * cpx + (((int)blockIdx.x) >> 3);
    const int gm = M >> 8;
    const int mblk = swz % gm, nblk = swz / gm;
    const int m0 = mblk << 8, n0 = nblk << 8;

    // staging source (per-thread): row = t>>2 (+128 for 2nd issue), 16B chunk
    // pre-swizzled so linear LDS slot (row, c) holds global chunk c ^ swz(row)
    const int srow = t >> 2;
    const int schk = ((t & 3) ^ (srow & 3) ^ ((srow >> 2) & 2)) * 8;
    const u16* gA = A  + (size_t)(m0 + srow) * K + schk;
    const u16* gB = Bt + (size_t)(n0 + srow) * K + schk;
    const size_t hstep = (size_t)128 * K;
    const int ldst = t * 8;

    // fragment read offsets (elems): slice is [256][32], chunk = g ^ swz(row)
    const int cxor = (g ^ (fm & 3) ^ ((fm >> 2) & 2)) * 8;
    const int aoff = (wm * 128 + fm) * 32 + cxor;            // A region at 0
    const int boff = 16384 + (wn * 64 + fm) * 32 + cxor;     // B region at +16384

    f32x4 acc[8][4];
#pragma unroll
    for (int i = 0; i < 8; i++)
#pragma unroll
        for (int j = 0; j < 4; j++) acc[i][j] = f32x4{0.f, 0.f, 0.f, 0.f};

    const int nk = K >> 6;

#define STG_A(BO, KT, KS) do { \
    const u16* s_ = gA + (size_t)(KT) * 64 + (KS) * 32; \
    async16(s_,         &lds[(BO) + (KS) * 8192 + ldst]); \
    async16(s_ + hstep, &lds[(BO) + (KS) * 8192 + 4096 + ldst]); } while (0)
#define STG_B(BO, KT, KS) do { \
    const u16* s_ = gB + (size_t)(KT) * 64 + (KS) * 32; \
    async16(s_,         &lds[(BO) + 16384 + (KS) * 8192 + ldst]); \
    async16(s_ + hstep, &lds[(BO) + 16384 + (KS) * 8192 + 4096 + ldst]); } while (0)

    bf16x8 a0[4], a1[4], bfr[4];

#define LD_A0(BO, KS) { _Pragma("unroll") for (int m_ = 0; m_ < 4; m_++) \
    a0[m_] = *(const bf16x8*)&lds[(BO) + (KS) * 8192 + aoff + m_ * 512]; }
#define LD_A1(BO, KS) { _Pragma("unroll") for (int m_ = 0; m_ < 4; m_++) \
    a1[m_] = *(const bf16x8*)&lds[(BO) + (KS) * 8192 + 2048 + aoff + m_ * 512]; }
#define LD_B(BO, KS) { _Pragma("unroll") for (int n_ = 0; n_ < 4; n_++) \
    bfr[n_] = *(const bf16x8*)&lds[(BO) + (KS) * 8192 + boff + n_ * 512]; }
#define MM(AR, MO) { _Pragma("unroll") for (int m_ = 0; m_ < 4; m_++) \
    _Pragma("unroll") for (int n_ = 0; n_ < 4; n_++) \
    acc[(MO) + m_][n_] = __builtin_amdgcn_mfma_f32_16x16x32_bf16(AR[m_], bfr[n_], acc[(MO) + m_][n_], 0, 0, 0); }
#define BARX __builtin_amdgcn_s_barrier()
#define LGKM0 asm volatile("s_waitcnt lgkmcnt(0)" ::: "memory")
#define VM(N_) asm volatile("s_waitcnt vmcnt(" #N_ ")" ::: "memory")
#define PHASE_MID BARX; LGKM0; __builtin_amdgcn_s_setprio(1)
#define PHASE_END __builtin_amdgcn_s_setprio(0); BARX

    // prologue: stage tile 0 (Aks0, Bks0, Aks1, Bks1), publish Aks0+Bks0
    STG_A(0, 0, 0); STG_B(0, 0, 0); STG_A(0, 0, 1); STG_B(0, 0, 1);
    VM(4); BARX;

#pragma unroll 1
    for (int kt = 0; kt < nk - 1; kt++) {
        const int bo = (kt & 1) << 15, nb = bo ^ 32768;
        // P0: frags m0-3,ks0 + B ks0 | stage next Aks0
        LD_A0(bo, 0); LD_B(bo, 0);
        STG_A(nb, kt + 1, 0);
        PHASE_MID; MM(a0, 0); PHASE_END;
        // P1: frags m4-7,ks0 | stage next Bks0 | publish this tile's ks1 slices
        LD_A1(bo, 0);
        STG_B(nb, kt + 1, 0);
        VM(4);
        PHASE_MID; MM(a1, 4); PHASE_END;
        // P2: frags m0-3,ks1 + B ks1 | stage next Aks1
        LD_A0(bo, 1); LD_B(bo, 1);
        STG_A(nb, kt + 1, 1);
        PHASE_MID; MM(a0, 0); PHASE_END;
        // P3: frags m4-7,ks1 | stage next Bks1 | publish next tile's ks0 slices
        LD_A1(bo, 1);
        STG_B(nb, kt + 1, 1);
        VM(4);
        PHASE_MID; MM(a1, 4); PHASE_END;
    }
    {   // tail tile: no staging, drain counts 4 -> 0
        const int bo = ((nk - 1) & 1) << 15;
        LD_A0(bo, 0); LD_B(bo, 0);
        PHASE_MID; MM(a0, 0); PHASE_END;
        LD_A1(bo, 0);
        VM(0);
        PHASE_MID; MM(a1, 4); PHASE_END;
        LD_A0(bo, 1); LD_B(bo, 1);
        PHASE_MID; MM(a0, 0); PHASE_END;
        LD_A1(bo, 1);
        PHASE_MID; MM(a1, 4); PHASE_END;
    }

    // C/D layout (16x16): col = lane&15, row = (lane>>4)*4 + reg
    const int crow0 = m0 + wm * 128 + g * 4;
    const int ccol = n0 + wn * 64 + fm;
#pragma unroll
    for (int mi = 0; mi < 8; mi++)
#pragma unroll
        for (int r = 0; r < 4; r++) {
            const size_t row = (size_t)(crow0 + mi * 16 + r);
            if (OUT_BF16) {
                u16* p = (u16*)Cout + row * N + ccol;
#pragma unroll
                for (int n_ = 0; n_ < 4; n_++) p[n_ * 16] = f2b(acc[mi][n_][r]);
            } else {
                float* p = (float*)Cout + row * N + ccol;
#pragma unroll
                for (int n_ = 0; n_ < 4; n_++) p[n_ * 16] = acc[mi][n_][r];
            }
        }
#undef STG_A
#undef STG_B
#undef LD_A0
#undef LD_A1
#undef LD_B
#undef MM
#undef BARX
#undef LGKM0
#undef VM
#undef PHASE_MID
#undef PHASE_END
}

// ---------------- RoPE + relayout ----------------
// qkv bf16 [tok][12288] -> Q,K [b][h][s][256] bf16 (rope applied), VT [b][h][256][s] bf16
__global__ __launch_bounds__(256) void rope_relayout(const int* __restrict__ pos_ids,
                                                     const u16* __restrict__ qkv,
                                                     u16* __restrict__ Qo,
                                                     u16* __restrict__ Ko,
                                                     u16* __restrict__ VTo) {
    __shared__ u16 sV[64 * 256];
    const int st = blockIdx.x, h = blockIdx.y, b = blockIdx.z;
    const int t = threadIdx.x;
    const int sbase = st * 64;

    {
        const u16* vbase = qkv + (size_t)(b * SEQ + sbase) * N3 + 2 * HID + h * HDIM;
        const int dcol = (t & 31) * 8;
        const int tokoff = t >> 5;
#pragma unroll
        for (int r = 0; r < 4; r++)
#pragma unroll
            for (int s8 = 0; s8 < 8; s8++) {
                int tok = r * 16 + s8 * 2 + tokoff;
                async16(vbase + (size_t)tok * N3 + dcol, &sV[r * 4096 + s8 * 512 + t * 8]);
            }
    }

    const int tok = t & 63, part = t >> 6;
    const int s = sbase + tok;
    const int pos = pos_ids[b * SEQ + s];
    const int isK = part >> 1, isPass = part & 1;
    const u16* src = qkv + (size_t)(b * SEQ + s) * N3 + isK * HID + h * HDIM + isPass * 128;
    u16* dst = (isK ? Ko : Qo) + ((size_t)((b * NHD + h) * SEQ + s)) * HDIM + isPass * 128;
    if (!isPass) {
        const float fpos = (float)pos;
#pragma unroll
        for (int c = 0; c < 8; c++) {
            bf16x8 xa = *(const bf16x8*)(src + c * 8);
            bf16x8 xb = *(const bf16x8*)(src + 64 + c * 8);
            union { u16 h[8]; uint4 v; } o1, o2;
#pragma unroll
            for (int j = 0; j < 8; j++) {
                int i = c * 8 + j;
                float invf = __expf((float)i * -0.14391156831212787f);
                float ang = fpos * invf;
                float sn, cs;
                __sincosf(ang, &sn, &cs);
                float x1 = (float)xa[j], x2 = (float)xb[j];
                o1.h[j] = f2b(x1 * cs - x2 * sn);
                o2.h[j] = f2b(x2 * cs + x1 * sn);
            }
            *(uint4*)(dst + c * 8)      = o1.v;
            *(uint4*)(dst + 64 + c * 8) = o2.v;
        }
    } else {
        const uint4* s4 = (const uint4*)src;
        uint4* d4 = (uint4*)dst;
#pragma unroll
        for (int c = 0; c < 16; c++) d4[c] = s4[c];
    }

    asm volatile("s_waitcnt vmcnt(0)" ::: "memory");
    __syncthreads();

    u16* vt = VTo + ((size_t)((b * NHD + h) * HDIM + t)) * SEQ + sbase;
#pragma unroll
    for (int g = 0; g < 8; g++) {
        union { u16 h[8]; uint4 v; } o;
#pragma unroll
        for (int j = 0; j < 8; j++) o.h[j] = sV[(g * 8 + j) * 256 + t];
        *(uint4*)(vt + g * 8) = o.v;
    }
}

// ---------------- flash attention (causal), per (b,h,64-row q-tile) ----------------
// sK [32 key][256 d] with column-chunks xor-swizzled by (key&7);
// sVT [256 d][32 s] with s-chunks xor-swizzled by (d&3).
__global__ __launch_bounds__(256) void attn_fwd(const u16* __restrict__ Q,
                                                const u16* __restrict__ K,
                                                const u16* __restrict__ VT,
                                                u16* __restrict__ attnO) {
    __shared__ u16 sK[32 * 256];
    __shared__ u16 sVT[256 * 32];
    __shared__ u16 sP[4 * 16 * 32];
    const int qt = (int)gridDim.x - 1 - (int)blockIdx.x;  // heavy tiles first
    const int h = blockIdx.y, b = blockIdx.z;
    const int t = threadIdx.x, lane = t & 63, w = t >> 6;
    const int fm = lane & 15, g = lane >> 4, fk = g * 8;
    const int qbase = qt * 64;
    const size_t head = ((size_t)(b * NHD + h)) * SEQ * HDIM;
    const u16* qptr = Q + head + (size_t)(qbase + w * 16 + fm) * HDIM;
    bf16x8 qf[8];
#pragma unroll
    for (int kk = 0; kk < 8; kk++) qf[kk] = *(const bf16x8*)(qptr + kk * 32 + fk);
    const f32x4 z = {0.f, 0.f, 0.f, 0.f};
    f32x4 O[16];
#pragma unroll
    for (int n = 0; n < 16; n++) O[n] = z;
    float mrow[4] = {-1e30f, -1e30f, -1e30f, -1e30f};
    float lrow[4] = {0.f, 0.f, 0.f, 0.f};
    const int nkt = qt * 2 + 2;
    const u16* kbaseP = K + head;
    const u16* vtbase = VT + head;
    const int qg_base = qbase + w * 16 + g * 4;

    for (int kb = 0; kb < nkt; kb++) {
        {
            const int krow = t >> 5;                            // key row within 8
            const int dcol = ((t & 31) ^ krow) * 8;             // swizzle by key&7
#pragma unroll
            for (int r = 0; r < 4; r++)
                async16(kbaseP + (size_t)(kb * 32 + r * 8 + krow) * HDIM + dcol,
                        &sK[r * 2048 + t * 8]);
            const int drow = t >> 2;
            const int scol = (((t & 3) ^ (drow & 3))) * 8;      // swizzle by d&3
#pragma unroll
            for (int r = 0; r < 4; r++)
                async16(vtbase + (size_t)(r * 64 + drow) * SEQ + kb * 32 + scol,
                        &sVT[r * 2048 + t * 8]);
        }
        asm volatile("s_waitcnt vmcnt(0)" ::: "memory");
        __syncthreads();

        f32x4 sc0 = z, sc1 = z;
#pragma unroll
        for (int kk = 0; kk < 8; kk++) {
            const int p = ((kk * 4 + g) ^ (fm & 7)) * 8;
            bf16x8 kf0 = *(const bf16x8*)&sK[fm * 256 + p];
            bf16x8 kf1 = *(const bf16x8*)&sK[(16 + fm) * 256 + p];
            sc0 = __builtin_amdgcn_mfma_f32_16x16x32_bf16(qf[kk], kf0, sc0, 0, 0, 0);
            sc1 = __builtin_amdgcn_mfma_f32_16x16x32_bf16(qf[kk], kf1, sc1, 0, 0, 0);
        }
        const int kg0 = kb * 32 + fm, kg1 = kg0 + 16;
        float alpha[4];
#pragma unroll
        for (int j = 0; j < 4; j++) {
            const int qg = qg_base + j;
            float s0 = (kg0 <= qg) ? sc0[j] * 0.0625f : -1e30f;
            float s1 = (kg1 <= qg) ? sc1[j] * 0.0625f : -1e30f;
            float mx = fmaxf(s0, s1);
            mx = fmaxf(mx, __shfl_xor(mx, 1, 64));
            mx = fmaxf(mx, __shfl_xor(mx, 2, 64));
            mx = fmaxf(mx, __shfl_xor(mx, 4, 64));
            mx = fmaxf(mx, __shfl_xor(mx, 8, 64));
            const float mn = fmaxf(mrow[j], mx);
            alpha[j] = __expf(mrow[j] - mn);
            mrow[j] = mn;
            float p0 = __expf(s0 - mn);
            float p1 = __expf(s1 - mn);
            float rs = p0 + p1;
            rs += __shfl_xor(rs, 1, 64);
            rs += __shfl_xor(rs, 2, 64);
            rs += __shfl_xor(rs, 4, 64);
            rs += __shfl_xor(rs, 8, 64);
            lrow[j] = lrow[j] * alpha[j] + rs;
            const int r = g * 4 + j;
            sP[w * 512 + r * 32 + fm]      = f2b(p0);
            sP[w * 512 + r * 32 + 16 + fm] = f2b(p1);
        }
#pragma unroll
        for (int n = 0; n < 16; n++) {
            O[n][0] *= alpha[0]; O[n][1] *= alpha[1];
            O[n][2] *= alpha[2]; O[n][3] *= alpha[3];
        }
        bf16x8 pf = *(const bf16x8*)&sP[w * 512 + fm * 32 + fk];
#pragma unroll
        for (int n = 0; n < 16; n++) {
            const int d = n * 16 + fm;
            bf16x8 vf = *(const bf16x8*)&sVT[d * 32 + ((g ^ (fm & 3)) << 3)];
            O[n] = __builtin_amdgcn_mfma_f32_16x16x32_bf16(pf, vf, O[n], 0, 0, 0);
        }
        __syncthreads();
    }
#pragma unroll
    for (int j = 0; j < 4; j++) {
        const int r = g * 4 + j;
        const float inv = 1.0f / lrow[j];
        u16* orow = attnO + (size_t)(b * SEQ + qbase + w * 16 + r) * HID + h * HDIM;
#pragma unroll
        for (int n = 0; n < 16; n++)
            orow[n * 16 + fm] = f2b(O[n][j] * inv);
    }
}

// ---------------- launch ----------------
extern "C" void kernel_launch(void* const* d_in, const int* in_sizes, int n_in,
                              void* d_out, int out_size, void* d_ws, size_t ws_size,
                              hipStream_t stream) {
    (void)in_sizes; (void)n_in; (void)out_size; (void)ws_size;
    const int*   pos    = (const int*)d_in[0];
    const float* hidden = (const float*)d_in[1];
    const float* wqkv   = (const float*)d_in[2];
    const float* wout   = (const float*)d_in[3];
    float* out = (float*)d_out;
    char* ws = (char*)d_ws;

    u16* hiddenB = (u16*)ws;                              //  33,554,432 B
    u16* wqkvT   = (u16*)(ws + (size_t)33554432);         // 100,663,296 B
    u16* woutT   = (u16*)(ws + (size_t)134217728);        //  33,554,432 B
    u16* qkv     = (u16*)(ws + (size_t)167772160);        // 100,663,296 B
    u16* Qb    = wqkvT;                 // after GEMM1, wqkvT is dead
    u16* Kb    = wqkvT + 16777216;
    u16* VTb   = wqkvT + 33554432;
    u16* attnB = qkv;                   // after rope, qkv is dead

    cast_bf16<<<dim3(TOK * HID / 8 / 256), 256, 0, stream>>>(
        (const float4*)hidden, (uint4*)hiddenB, TOK * HID / 8);
    tcast<<<dim3(N3 / 64, HID / 64), 256, 0, stream>>>(wqkv, wqkvT, HID, N3);
    tcast<<<dim3(HID / 64, HID / 64), 256, 0, stream>>>(wout, woutT, HID, HID);
    gemm256<true><<<dim3((TOK / 256) * (N3 / 256)), 512, 0, stream>>>(
        hiddenB, wqkvT, qkv, TOK, N3, HID);
    rope_relayout<<<dim3(SEQ / 64, NHD, BB), 256, 0, stream>>>(pos, qkv, Qb, Kb, VTb);
    attn_fwd<<<dim3(SEQ / 64, NHD, BB), 256, 0, stream>>>(Qb, Kb, VTb, attnB);
    gemm256<false><<<dim3((TOK / 256) * (HID / 256)), 512, 0, stream>>>(
        attnB, woutT, out, TOK, HID, HID);
}

// Round 3
// 1098.543 us; speedup vs baseline: 1.2716x; 1.1015x over previous
//
#include <hip/hip_runtime.h>
#include <cstdint>

#define HID  4096
#define NHD  16
#define HDIM 256
#define SEQ  1024
#define BB   4
#define N3   12288
#define TOK  4096

typedef unsigned short u16;
typedef __bf16 bf16x8 __attribute__((ext_vector_type(8)));
typedef float  f32x4  __attribute__((ext_vector_type(4)));
typedef float  f32x16 __attribute__((ext_vector_type(16)));

__device__ __forceinline__ u16 f2b(float f) {
    unsigned u = __builtin_bit_cast(unsigned, f);
    u += 0x7fffu + ((u >> 16) & 1u);          // RNE
    return (u16)(u >> 16);
}
__device__ __forceinline__ float b2f(u16 v) {
    unsigned u = ((unsigned)v) << 16;
    return __builtin_bit_cast(float, u);
}

typedef __attribute__((address_space(3))) unsigned       lds_u32;
typedef const __attribute__((address_space(1))) unsigned glb_u32;
__device__ __forceinline__ void async16(const void* g, void* l) {
    __builtin_amdgcn_global_load_lds((glb_u32*)g, (lds_u32*)l, 16, 0, 0);
}

// ---------------- cast fp32 -> bf16 (row-major) ----------------
__global__ __launch_bounds__(256) void cast_bf16(const float4* __restrict__ in,
                                                 uint4* __restrict__ out, int n8) {
    int i = blockIdx.x * 256 + threadIdx.x;
    if (i >= n8) return;
    float4 a = in[2 * i], b = in[2 * i + 1];
    union { u16 h[8]; uint4 v; } o;
    o.h[0] = f2b(a.x); o.h[1] = f2b(a.y); o.h[2] = f2b(a.z); o.h[3] = f2b(a.w);
    o.h[4] = f2b(b.x); o.h[5] = f2b(b.y); o.h[6] = f2b(b.z); o.h[7] = f2b(b.w);
    out[i] = o.v;
}

// ---------------- transpose-cast: in[R][C] fp32 -> out[C][R] bf16 ----------------
__global__ __launch_bounds__(256) void tcast(const float* __restrict__ in,
                                             u16* __restrict__ out, int R, int C) {
    __shared__ u16 sT[64 * 80];
    const int c0 = blockIdx.x * 64, r0 = blockIdx.y * 64;
    const int t = threadIdx.x;
    const int rr = t >> 4, cc = (t & 15) * 4;
    for (int rnd = 0; rnd < 4; rnd++) {
        int r = rnd * 16 + rr;
        float4 v = *(const float4*)(in + (size_t)(r0 + r) * C + c0 + cc);
        sT[(cc + 0) * 80 + r] = f2b(v.x);
        sT[(cc + 1) * 80 + r] = f2b(v.y);
        sT[(cc + 2) * 80 + r] = f2b(v.z);
        sT[(cc + 3) * 80 + r] = f2b(v.w);
    }
    __syncthreads();
    const int orow = t >> 2, oc = (t & 3) * 16;
    u16* dst = out + (size_t)(c0 + orow) * R + r0 + oc;
    *(uint4*)dst       = *(uint4*)&sT[orow * 80 + oc];
    *(uint4*)(dst + 8) = *(uint4*)&sT[orow * 80 + oc + 8];
}

// ---------------- bf16 GEMM: C[M][N] = A[M][K] * Bt[N][K]^T ----------------
// 256x256 tile, BK=64, 512 threads = 8 waves (2M x 4N), 16x16x32 MFMA.
// LDS: 2 double-buffers x (A,B) x 2 k-slices of [256 rows][32 k] bf16 = 128 KiB.
// Chunk swizzle: swz(row) = (row&3) ^ ((row>>2)&2) -- row bit 3 XORed into chunk
// bit 1 (the 512B-alias bit) => conflict-free ds_read_b128 (verified: conflicts=0).
// 4 phases per K-tile: {ds_read 8|4 frags, stage 1 k-slice (2x gload_lds),
//  raw s_barrier, lgkmcnt(0), setprio(1), 16 MFMA, setprio(0), barrier}.
// Counted vmcnt(4) publish at end of P1/P3 only (never vmcnt(0) in main loop).
template <bool OUT_BF16>
__global__ __launch_bounds__(512, 2) void gemm256(const u16* __restrict__ A,
                                                  const u16* __restrict__ Bt,
                                                  void* __restrict__ Cout,
                                                  int M, int N, int K) {
    __shared__ alignas(16) u16 lds[65536];   // 128 KiB
    const int t = threadIdx.x;
    const int lane = t & 63, w = t >> 6;
    const int wm = w >> 2, wn = w & 3;
    const int fm = lane & 15, g = lane >> 4;

    // XCD-aware block swizzle (grid is 1-D, nwg % 8 == 0 for our shapes)
    const int nwg = (int)gridDim.x;
    const int cpx = nwg >> 3;
    const int swz = (((int)blockIdx.x) & 7) * cpx + (((int)blockIdx.x) >> 3);
    const int gm = M >> 8;
    const int mblk = swz % gm, nblk = swz / gm;
    const int m0 = mblk << 8, n0 = nblk << 8;

    // staging source (per-thread): row = t>>2 (+128 for 2nd issue), 16B chunk
    // pre-swizzled so linear LDS slot (row, c) holds global chunk c ^ swz(row)
    const int srow = t >> 2;
    const int schk = ((t & 3) ^ (srow & 3) ^ ((srow >> 2) & 2)) * 8;
    const u16* gA = A  + (size_t)(m0 + srow) * K + schk;
    const u16* gB = Bt + (size_t)(n0 + srow) * K + schk;
    const size_t hstep = (size_t)128 * K;
    const int ldst = t * 8;

    // fragment read offsets (elems): slice is [256][32], chunk = g ^ swz(row)
    const int cxor = (g ^ (fm & 3) ^ ((fm >> 2) & 2)) * 8;
    const int aoff = (wm * 128 + fm) * 32 + cxor;            // A region at 0
    const int boff = 16384 + (wn * 64 + fm) * 32 + cxor;     // B region at +16384

    f32x4 acc[8][4];
#pragma unroll
    for (int i = 0; i < 8; i++)
#pragma unroll
        for (int j = 0; j < 4; j++) acc[i][j] = f32x4{0.f, 0.f, 0.f, 0.f};

    const int nk = K >> 6;

#define STG_A(BO, KT, KS) do { \
    const u16* s_ = gA + (size_t)(KT) * 64 + (KS) * 32; \
    async16(s_,         &lds[(BO) + (KS) * 8192 + ldst]); \
    async16(s_ + hstep, &lds[(BO) + (KS) * 8192 + 4096 + ldst]); } while (0)
#define STG_B(BO, KT, KS) do { \
    const u16* s_ = gB + (size_t)(KT) * 64 + (KS) * 32; \
    async16(s_,         &lds[(BO) + 16384 + (KS) * 8192 + ldst]); \
    async16(s_ + hstep, &lds[(BO) + 16384 + (KS) * 8192 + 4096 + ldst]); } while (0)

    bf16x8 a0[4], a1[4], bfr[4];

#define LD_A0(BO, KS) { _Pragma("unroll") for (int m_ = 0; m_ < 4; m_++) \
    a0[m_] = *(const bf16x8*)&lds[(BO) + (KS) * 8192 + aoff + m_ * 512]; }
#define LD_A1(BO, KS) { _Pragma("unroll") for (int m_ = 0; m_ < 4; m_++) \
    a1[m_] = *(const bf16x8*)&lds[(BO) + (KS) * 8192 + 2048 + aoff + m_ * 512]; }
#define LD_B(BO, KS) { _Pragma("unroll") for (int n_ = 0; n_ < 4; n_++) \
    bfr[n_] = *(const bf16x8*)&lds[(BO) + (KS) * 8192 + boff + n_ * 512]; }
#define MM(AR, MO) { _Pragma("unroll") for (int m_ = 0; m_ < 4; m_++) \
    _Pragma("unroll") for (int n_ = 0; n_ < 4; n_++) \
    acc[(MO) + m_][n_] = __builtin_amdgcn_mfma_f32_16x16x32_bf16(AR[m_], bfr[n_], acc[(MO) + m_][n_], 0, 0, 0); }
#define BARX __builtin_amdgcn_s_barrier()
#define LGKM0 asm volatile("s_waitcnt lgkmcnt(0)" ::: "memory")
#define VM(N_) asm volatile("s_waitcnt vmcnt(" #N_ ")" ::: "memory")
#define PHASE_MID BARX; LGKM0; __builtin_amdgcn_s_setprio(1)
#define PHASE_END __builtin_amdgcn_s_setprio(0); BARX

    // prologue: stage tile 0 (Aks0, Bks0, Aks1, Bks1), publish Aks0+Bks0
    STG_A(0, 0, 0); STG_B(0, 0, 0); STG_A(0, 0, 1); STG_B(0, 0, 1);
    VM(4); BARX;

#pragma unroll 1
    for (int kt = 0; kt < nk - 1; kt++) {
        const int bo = (kt & 1) << 15, nb = bo ^ 32768;
        // P0: frags m0-3,ks0 + B ks0 | stage next Aks0
        LD_A0(bo, 0); LD_B(bo, 0);
        STG_A(nb, kt + 1, 0);
        PHASE_MID; MM(a0, 0); PHASE_END;
        // P1: frags m4-7,ks0 | stage next Bks0 | publish this tile's ks1 slices
        LD_A1(bo, 0);
        STG_B(nb, kt + 1, 0);
        VM(4);
        PHASE_MID; MM(a1, 4); PHASE_END;
        // P2: frags m0-3,ks1 + B ks1 | stage next Aks1
        LD_A0(bo, 1); LD_B(bo, 1);
        STG_A(nb, kt + 1, 1);
        PHASE_MID; MM(a0, 0); PHASE_END;
        // P3: frags m4-7,ks1 | stage next Bks1 | publish next tile's ks0 slices
        LD_A1(bo, 1);
        STG_B(nb, kt + 1, 1);
        VM(4);
        PHASE_MID; MM(a1, 4); PHASE_END;
    }
    {   // tail tile: no staging, drain counts 4 -> 0
        const int bo = ((nk - 1) & 1) << 15;
        LD_A0(bo, 0); LD_B(bo, 0);
        PHASE_MID; MM(a0, 0); PHASE_END;
        LD_A1(bo, 0);
        VM(0);
        PHASE_MID; MM(a1, 4); PHASE_END;
        LD_A0(bo, 1); LD_B(bo, 1);
        PHASE_MID; MM(a0, 0); PHASE_END;
        LD_A1(bo, 1);
        PHASE_MID; MM(a1, 4); PHASE_END;
    }

    // C/D layout (16x16): col = lane&15, row = (lane>>4)*4 + reg
    const int crow0 = m0 + wm * 128 + g * 4;
    const int ccol = n0 + wn * 64 + fm;
#pragma unroll
    for (int mi = 0; mi < 8; mi++)
#pragma unroll
        for (int r = 0; r < 4; r++) {
            const size_t row = (size_t)(crow0 + mi * 16 + r);
            if (OUT_BF16) {
                u16* p = (u16*)Cout + row * N + ccol;
#pragma unroll
                for (int n_ = 0; n_ < 4; n_++) p[n_ * 16] = f2b(acc[mi][n_][r]);
            } else {
                float* p = (float*)Cout + row * N + ccol;
#pragma unroll
                for (int n_ = 0; n_ < 4; n_++) p[n_ * 16] = acc[mi][n_][r];
            }
        }
#undef STG_A
#undef STG_B
#undef LD_A0
#undef LD_A1
#undef LD_B
#undef MM
#undef BARX
#undef LGKM0
#undef VM
#undef PHASE_MID
#undef PHASE_END
}

// ---------------- RoPE cos/sin table: tab[b*SEQ+s][i] = (cos,sin)(pos*invf(i)) ----
// Removes the 32x-redundant (16 heads x {Q,K}) transcendental recompute.
__global__ __launch_bounds__(256) void rope_tab(const int* __restrict__ pos_ids,
                                                float2* __restrict__ tab) {
    const int idx = blockIdx.x * 256 + threadIdx.x;   // over B*SEQ*64
    const int bs = idx >> 6, i = idx & 63;
    const float invf = __expf((float)i * -0.14391156831212787f);
    const float ang = (float)pos_ids[bs] * invf;
    float sn, cs;
    __sincosf(ang, &sn, &cs);
    tab[idx] = make_float2(cs, sn);
}

// ---------------- RoPE + relayout ----------------
// qkv bf16 [tok][12288] -> Q,K [b][h][s][256] bf16 (rope applied), VT [b][h][256][s] bf16
__global__ __launch_bounds__(256) void rope_relayout(const float2* __restrict__ tab,
                                                     const u16* __restrict__ qkv,
                                                     u16* __restrict__ Qo,
                                                     u16* __restrict__ Ko,
                                                     u16* __restrict__ VTo) {
    __shared__ u16 sV[64 * 256];
    const int st = blockIdx.x, h = blockIdx.y, b = blockIdx.z;
    const int t = threadIdx.x;
    const int sbase = st * 64;

    {
        const u16* vbase = qkv + (size_t)(b * SEQ + sbase) * N3 + 2 * HID + h * HDIM;
        const int dcol = (t & 31) * 8;
        const int tokoff = t >> 5;
#pragma unroll
        for (int r = 0; r < 4; r++)
#pragma unroll
            for (int s8 = 0; s8 < 8; s8++) {
                int tok = r * 16 + s8 * 2 + tokoff;
                async16(vbase + (size_t)tok * N3 + dcol, &sV[r * 4096 + s8 * 512 + t * 8]);
            }
    }

    const int tok = t & 63, part = t >> 6;
    const int s = sbase + tok;
    const int isK = part >> 1, isPass = part & 1;
    const u16* src = qkv + (size_t)(b * SEQ + s) * N3 + isK * HID + h * HDIM + isPass * 128;
    u16* dst = (isK ? Ko : Qo) + ((size_t)((b * NHD + h) * SEQ + s)) * HDIM + isPass * 128;
    if (!isPass) {
        const float2* trow = tab + ((size_t)(b * SEQ + s) << 6);
#pragma unroll
        for (int c = 0; c < 8; c++) {
            bf16x8 xa = *(const bf16x8*)(src + c * 8);
            bf16x8 xb = *(const bf16x8*)(src + 64 + c * 8);
            union { u16 h[8]; uint4 v; } o1, o2;
#pragma unroll
            for (int j = 0; j < 8; j++) {
                float2 t2 = trow[c * 8 + j];
                const float cs = t2.x, sn = t2.y;
                float x1 = (float)xa[j], x2 = (float)xb[j];
                o1.h[j] = f2b(x1 * cs - x2 * sn);
                o2.h[j] = f2b(x2 * cs + x1 * sn);
            }
            *(uint4*)(dst + c * 8)      = o1.v;
            *(uint4*)(dst + 64 + c * 8) = o2.v;
        }
    } else {
        const uint4* s4 = (const uint4*)src;
        uint4* d4 = (uint4*)dst;
#pragma unroll
        for (int c = 0; c < 16; c++) d4[c] = s4[c];
    }

    asm volatile("s_waitcnt vmcnt(0)" ::: "memory");
    __syncthreads();

    u16* vt = VTo + ((size_t)((b * NHD + h) * HDIM + t)) * SEQ + sbase;
#pragma unroll
    for (int g = 0; g < 8; g++) {
        union { u16 h[8]; uint4 v; } o;
#pragma unroll
        for (int j = 0; j < 8; j++) o.h[j] = sV[(g * 8 + j) * 256 + t];
        *(uint4*)(vt + g * 8) = o.v;
    }
}

// ---------------- flash attention (causal), per (b,h,64-row q-tile) ----------------
// Double-buffered K/V staging (min 2-phase pipeline): stage tile kb+1 BEFORE
// computing tile kb; one vmcnt(0)+barrier per tile (load latency hides under
// ~1000cy of QK/softmax/PV).  setprio(1) around MFMA clusters (T5).
// Exact defer-rescale: skip the O-rescale pass when no row's max grew (alpha==1).
// sK [32 key][256 d] col-chunks xor-swizzled by (key&7); sVT [256 d][32 s]
// s-chunks xor-swizzled by (d&3).
__global__ __launch_bounds__(256) void attn_fwd(const u16* __restrict__ Q,
                                                const u16* __restrict__ K,
                                                const u16* __restrict__ VT,
                                                u16* __restrict__ attnO) {
    __shared__ u16 sK[2][32 * 256];
    __shared__ u16 sVT[2][32 * 256];
    __shared__ u16 sP[4 * 16 * 32];
    const int qt = (int)gridDim.x - 1 - (int)blockIdx.x;  // heavy tiles first
    const int h = blockIdx.y, b = blockIdx.z;
    const int t = threadIdx.x, lane = t & 63, w = t >> 6;
    const int fm = lane & 15, g = lane >> 4, fk = g * 8;
    const int qbase = qt * 64;
    const size_t head = ((size_t)(b * NHD + h)) * SEQ * HDIM;
    const u16* qptr = Q + head + (size_t)(qbase + w * 16 + fm) * HDIM;
    bf16x8 qf[8];
#pragma unroll
    for (int kk = 0; kk < 8; kk++) qf[kk] = *(const bf16x8*)(qptr + kk * 32 + fk);
    const f32x4 z = {0.f, 0.f, 0.f, 0.f};
    f32x4 O[16];
#pragma unroll
    for (int n = 0; n < 16; n++) O[n] = z;
    float mrow[4] = {-1e30f, -1e30f, -1e30f, -1e30f};
    float lrow[4] = {0.f, 0.f, 0.f, 0.f};
    const int nkt = qt * 2 + 2;
    const u16* kbaseP = K + head;
    const u16* vtbase = VT + head;
    const int qg_base = qbase + w * 16 + g * 4;

    const int krow = t >> 5;                       // staging addr helpers
    const int dcol = ((t & 31) ^ krow) * 8;        // K swizzle by key&7
    const int drow = t >> 2;
    const int scol = ((t & 3) ^ (drow & 3)) * 8;   // VT swizzle by d&3

#define STAGE_KV(BUF, KB) do { \
    _Pragma("unroll") for (int r_ = 0; r_ < 4; r_++) \
        async16(kbaseP + (size_t)((KB) * 32 + r_ * 8 + krow) * HDIM + dcol, \
                &sK[BUF][r_ * 2048 + t * 8]); \
    _Pragma("unroll") for (int r_ = 0; r_ < 4; r_++) \
        async16(vtbase + (size_t)(r_ * 64 + drow) * SEQ + (KB) * 32 + scol, \
                &sVT[BUF][r_ * 2048 + t * 8]); } while (0)

    STAGE_KV(0, 0);
    asm volatile("s_waitcnt vmcnt(0)" ::: "memory");
    __syncthreads();

    for (int kb = 0; kb < nkt; kb++) {
        const int cur = kb & 1;
        if (kb + 1 < nkt) STAGE_KV(cur ^ 1, kb + 1);   // overlaps with compute below

        f32x4 sc0 = z, sc1 = z;
        __builtin_amdgcn_s_setprio(1);
#pragma unroll
        for (int kk = 0; kk < 8; kk++) {
            const int p = ((kk * 4 + g) ^ (fm & 7)) * 8;
            bf16x8 kf0 = *(const bf16x8*)&sK[cur][fm * 256 + p];
            bf16x8 kf1 = *(const bf16x8*)&sK[cur][(16 + fm) * 256 + p];
            sc0 = __builtin_amdgcn_mfma_f32_16x16x32_bf16(qf[kk], kf0, sc0, 0, 0, 0);
            sc1 = __builtin_amdgcn_mfma_f32_16x16x32_bf16(qf[kk], kf1, sc1, 0, 0, 0);
        }
        __builtin_amdgcn_s_setprio(0);
        const int kg0 = kb * 32 + fm, kg1 = kg0 + 16;
        float alpha[4];
        bool grow = false;
#pragma unroll
        for (int j = 0; j < 4; j++) {
            const int qg = qg_base + j;
            float s0 = (kg0 <= qg) ? sc0[j] * 0.0625f : -1e30f;
            float s1 = (kg1 <= qg) ? sc1[j] * 0.0625f : -1e30f;
            float mx = fmaxf(s0, s1);
            mx = fmaxf(mx, __shfl_xor(mx, 1, 64));
            mx = fmaxf(mx, __shfl_xor(mx, 2, 64));
            mx = fmaxf(mx, __shfl_xor(mx, 4, 64));
            mx = fmaxf(mx, __shfl_xor(mx, 8, 64));
            const float mn = fmaxf(mrow[j], mx);
            grow = grow || (mn > mrow[j]);
            alpha[j] = __expf(mrow[j] - mn);
            mrow[j] = mn;
            float p0 = __expf(s0 - mn);
            float p1 = __expf(s1 - mn);
            float rs = p0 + p1;
            rs += __shfl_xor(rs, 1, 64);
            rs += __shfl_xor(rs, 2, 64);
            rs += __shfl_xor(rs, 4, 64);
            rs += __shfl_xor(rs, 8, 64);
            lrow[j] = lrow[j] * alpha[j] + rs;
            const int r = g * 4 + j;
            sP[w * 512 + r * 32 + fm]      = f2b(p0);
            sP[w * 512 + r * 32 + 16 + fm] = f2b(p1);
        }
        if (__any(grow)) {          // exact skip: alpha==1 for all rows otherwise
#pragma unroll
            for (int n = 0; n < 16; n++) {
                O[n][0] *= alpha[0]; O[n][1] *= alpha[1];
                O[n][2] *= alpha[2]; O[n][3] *= alpha[3];
            }
        }
        bf16x8 pf = *(const bf16x8*)&sP[w * 512 + fm * 32 + fk];
        __builtin_amdgcn_s_setprio(1);
#pragma unroll
        for (int n = 0; n < 16; n++) {
            const int d = n * 16 + fm;
            bf16x8 vf = *(const bf16x8*)&sVT[cur][d * 32 + ((g ^ (fm & 3)) << 3)];
            O[n] = __builtin_amdgcn_mfma_f32_16x16x32_bf16(pf, vf, O[n], 0, 0, 0);
        }
        __builtin_amdgcn_s_setprio(0);
        asm volatile("s_waitcnt vmcnt(0)" ::: "memory");  // next-tile loads landed
        __syncthreads();                                  // publish + protect overwrite
    }
#undef STAGE_KV
#pragma unroll
    for (int j = 0; j < 4; j++) {
        const int r = g * 4 + j;
        const float inv = 1.0f / lrow[j];
        u16* orow = attnO + (size_t)(b * SEQ + qbase + w * 16 + r) * HID + h * HDIM;
#pragma unroll
        for (int n = 0; n < 16; n++)
            orow[n * 16 + fm] = f2b(O[n][j] * inv);
    }
}

// ---------------- launch ----------------
extern "C" void kernel_launch(void* const* d_in, const int* in_sizes, int n_in,
                              void* d_out, int out_size, void* d_ws, size_t ws_size,
                              hipStream_t stream) {
    (void)in_sizes; (void)n_in; (void)out_size; (void)ws_size;
    const int*   pos    = (const int*)d_in[0];
    const float* hidden = (const float*)d_in[1];
    const float* wqkv   = (const float*)d_in[2];
    const float* wout   = (const float*)d_in[3];
    float* out = (float*)d_out;
    char* ws = (char*)d_ws;

    u16* hiddenB = (u16*)ws;                              //  33,554,432 B
    u16* wqkvT   = (u16*)(ws + (size_t)33554432);         // 100,663,296 B
    u16* woutT   = (u16*)(ws + (size_t)134217728);        //  33,554,432 B
    u16* qkv     = (u16*)(ws + (size_t)167772160);        // 100,663,296 B
    u16* Qb    = wqkvT;                 // after GEMM1, wqkvT is dead
    u16* Kb    = wqkvT + 16777216;
    u16* VTb   = wqkvT + 33554432;
    u16* attnB = qkv;                   // after rope, qkv is dead
    float2* tabF = (float2*)ws;         // after GEMM1, hiddenB is dead (2 MB table)

    cast_bf16<<<dim3(TOK * HID / 8 / 256), 256, 0, stream>>>(
        (const float4*)hidden, (uint4*)hiddenB, TOK * HID / 8);
    tcast<<<dim3(N3 / 64, HID / 64), 256, 0, stream>>>(wqkv, wqkvT, HID, N3);
    tcast<<<dim3(HID / 64, HID / 64), 256, 0, stream>>>(wout, woutT, HID, HID);
    gemm256<true><<<dim3((TOK / 256) * (N3 / 256)), 512, 0, stream>>>(
        hiddenB, wqkvT, qkv, TOK, N3, HID);
    rope_tab<<<dim3(BB * SEQ * 64 / 256), 256, 0, stream>>>(pos, tabF);
    rope_relayout<<<dim3(SEQ / 64, NHD, BB), 256, 0, stream>>>(tabF, qkv, Qb, Kb, VTb);
    attn_fwd<<<dim3(SEQ / 64, NHD, BB), 256, 0, stream>>>(Qb, Kb, VTb, attnB);
    gemm256<false><<<dim3((TOK / 256) * (HID / 256)), 512, 0, stream>>>(
        attnB, woutT, out, TOK, HID, HID);
}

// Round 4
// 1014.617 us; speedup vs baseline: 1.3768x; 1.0827x over previous
//
#include <hip/hip_runtime.h>
#include <cstdint>

#define HID  4096
#define NHD  16
#define HDIM 256
#define SEQ  1024
#define BB   4
#define N3   12288
#define TOK  4096

typedef unsigned short u16;
typedef __bf16 bf16x8 __attribute__((ext_vector_type(8)));
typedef float  f32x4  __attribute__((ext_vector_type(4)));
typedef float  f32x16 __attribute__((ext_vector_type(16)));

__device__ __forceinline__ u16 f2b(float f) {
    unsigned u = __builtin_bit_cast(unsigned, f);
    u += 0x7fffu + ((u >> 16) & 1u);          // RNE
    return (u16)(u >> 16);
}
__device__ __forceinline__ float b2f(u16 v) {
    unsigned u = ((unsigned)v) << 16;
    return __builtin_bit_cast(float, u);
}
__device__ __forceinline__ unsigned cvt_pk_bf16(float lo, float hi) {
    unsigned r;
    asm("v_cvt_pk_bf16_f32 %0, %1, %2" : "=v"(r) : "v"(lo), "v"(hi));
    return r;
}

typedef __attribute__((address_space(3))) unsigned       lds_u32;
typedef const __attribute__((address_space(1))) unsigned glb_u32;
__device__ __forceinline__ void async16(const void* g, void* l) {
    __builtin_amdgcn_global_load_lds((glb_u32*)g, (lds_u32*)l, 16, 0, 0);
}

// ---------------- cast fp32 -> bf16 (row-major) ----------------
__global__ __launch_bounds__(256) void cast_bf16(const float4* __restrict__ in,
                                                 uint4* __restrict__ out, int n8) {
    int i = blockIdx.x * 256 + threadIdx.x;
    if (i >= n8) return;
    float4 a = in[2 * i], b = in[2 * i + 1];
    union { u16 h[8]; uint4 v; } o;
    o.h[0] = f2b(a.x); o.h[1] = f2b(a.y); o.h[2] = f2b(a.z); o.h[3] = f2b(a.w);
    o.h[4] = f2b(b.x); o.h[5] = f2b(b.y); o.h[6] = f2b(b.z); o.h[7] = f2b(b.w);
    out[i] = o.v;
}

// ---------------- transpose-cast: in[R][C] fp32 -> out[C][R] bf16 ----------------
__global__ __launch_bounds__(256) void tcast(const float* __restrict__ in,
                                             u16* __restrict__ out, int R, int C) {
    __shared__ u16 sT[64 * 80];
    const int c0 = blockIdx.x * 64, r0 = blockIdx.y * 64;
    const int t = threadIdx.x;
    const int rr = t >> 4, cc = (t & 15) * 4;
    for (int rnd = 0; rnd < 4; rnd++) {
        int r = rnd * 16 + rr;
        float4 v = *(const float4*)(in + (size_t)(r0 + r) * C + c0 + cc);
        sT[(cc + 0) * 80 + r] = f2b(v.x);
        sT[(cc + 1) * 80 + r] = f2b(v.y);
        sT[(cc + 2) * 80 + r] = f2b(v.z);
        sT[(cc + 3) * 80 + r] = f2b(v.w);
    }
    __syncthreads();
    const int orow = t >> 2, oc = (t & 3) * 16;
    u16* dst = out + (size_t)(c0 + orow) * R + r0 + oc;
    *(uint4*)dst       = *(uint4*)&sT[orow * 80 + oc];
    *(uint4*)(dst + 8) = *(uint4*)&sT[orow * 80 + oc + 8];
}

// ---------------- bf16 GEMM: C[M][N] = A[M][K] * Bt[N][K]^T ----------------
// 256x256 tile, BK=64, 512 threads = 8 waves (2M x 4N), 16x16x32 MFMA.
// (unchanged from round 3 -- control group; conflicts=0, MfmaUtil ~49%)
template <bool OUT_BF16>
__global__ __launch_bounds__(512, 2) void gemm256(const u16* __restrict__ A,
                                                  const u16* __restrict__ Bt,
                                                  void* __restrict__ Cout,
                                                  int M, int N, int K) {
    __shared__ alignas(16) u16 lds[65536];   // 128 KiB
    const int t = threadIdx.x;
    const int lane = t & 63, w = t >> 6;
    const int wm = w >> 2, wn = w & 3;
    const int fm = lane & 15, g = lane >> 4;

    const int nwg = (int)gridDim.x;
    const int cpx = nwg >> 3;
    const int swz = (((int)blockIdx.x) & 7) * cpx + (((int)blockIdx.x) >> 3);
    const int gm = M >> 8;
    const int mblk = swz % gm, nblk = swz / gm;
    const int m0 = mblk << 8, n0 = nblk << 8;

    const int srow = t >> 2;
    const int schk = ((t & 3) ^ (srow & 3) ^ ((srow >> 2) & 2)) * 8;
    const u16* gA = A  + (size_t)(m0 + srow) * K + schk;
    const u16* gB = Bt + (size_t)(n0 + srow) * K + schk;
    const size_t hstep = (size_t)128 * K;
    const int ldst = t * 8;

    const int cxor = (g ^ (fm & 3) ^ ((fm >> 2) & 2)) * 8;
    const int aoff = (wm * 128 + fm) * 32 + cxor;            // A region at 0
    const int boff = 16384 + (wn * 64 + fm) * 32 + cxor;     // B region at +16384

    f32x4 acc[8][4];
#pragma unroll
    for (int i = 0; i < 8; i++)
#pragma unroll
        for (int j = 0; j < 4; j++) acc[i][j] = f32x4{0.f, 0.f, 0.f, 0.f};

    const int nk = K >> 6;

#define STG_A(BO, KT, KS) do { \
    const u16* s_ = gA + (size_t)(KT) * 64 + (KS) * 32; \
    async16(s_,         &lds[(BO) + (KS) * 8192 + ldst]); \
    async16(s_ + hstep, &lds[(BO) + (KS) * 8192 + 4096 + ldst]); } while (0)
#define STG_B(BO, KT, KS) do { \
    const u16* s_ = gB + (size_t)(KT) * 64 + (KS) * 32; \
    async16(s_,         &lds[(BO) + 16384 + (KS) * 8192 + ldst]); \
    async16(s_ + hstep, &lds[(BO) + 16384 + (KS) * 8192 + 4096 + ldst]); } while (0)

    bf16x8 a0[4], a1[4], bfr[4];

#define LD_A0(BO, KS) { _Pragma("unroll") for (int m_ = 0; m_ < 4; m_++) \
    a0[m_] = *(const bf16x8*)&lds[(BO) + (KS) * 8192 + aoff + m_ * 512]; }
#define LD_A1(BO, KS) { _Pragma("unroll") for (int m_ = 0; m_ < 4; m_++) \
    a1[m_] = *(const bf16x8*)&lds[(BO) + (KS) * 8192 + 2048 + aoff + m_ * 512]; }
#define LD_B(BO, KS) { _Pragma("unroll") for (int n_ = 0; n_ < 4; n_++) \
    bfr[n_] = *(const bf16x8*)&lds[(BO) + (KS) * 8192 + boff + n_ * 512]; }
#define MM(AR, MO) { _Pragma("unroll") for (int m_ = 0; m_ < 4; m_++) \
    _Pragma("unroll") for (int n_ = 0; n_ < 4; n_++) \
    acc[(MO) + m_][n_] = __builtin_amdgcn_mfma_f32_16x16x32_bf16(AR[m_], bfr[n_], acc[(MO) + m_][n_], 0, 0, 0); }
#define BARX __builtin_amdgcn_s_barrier()
#define LGKM0 asm volatile("s_waitcnt lgkmcnt(0)" ::: "memory")
#define VM(N_) asm volatile("s_waitcnt vmcnt(" #N_ ")" ::: "memory")
#define PHASE_MID BARX; LGKM0; __builtin_amdgcn_s_setprio(1)
#define PHASE_END __builtin_amdgcn_s_setprio(0); BARX

    STG_A(0, 0, 0); STG_B(0, 0, 0); STG_A(0, 0, 1); STG_B(0, 0, 1);
    VM(4); BARX;

#pragma unroll 1
    for (int kt = 0; kt < nk - 1; kt++) {
        const int bo = (kt & 1) << 15, nb = bo ^ 32768;
        LD_A0(bo, 0); LD_B(bo, 0);
        STG_A(nb, kt + 1, 0);
        PHASE_MID; MM(a0, 0); PHASE_END;
        LD_A1(bo, 0);
        STG_B(nb, kt + 1, 0);
        VM(4);
        PHASE_MID; MM(a1, 4); PHASE_END;
        LD_A0(bo, 1); LD_B(bo, 1);
        STG_A(nb, kt + 1, 1);
        PHASE_MID; MM(a0, 0); PHASE_END;
        LD_A1(bo, 1);
        STG_B(nb, kt + 1, 1);
        VM(4);
        PHASE_MID; MM(a1, 4); PHASE_END;
    }
    {
        const int bo = ((nk - 1) & 1) << 15;
        LD_A0(bo, 0); LD_B(bo, 0);
        PHASE_MID; MM(a0, 0); PHASE_END;
        LD_A1(bo, 0);
        VM(0);
        PHASE_MID; MM(a1, 4); PHASE_END;
        LD_A0(bo, 1); LD_B(bo, 1);
        PHASE_MID; MM(a0, 0); PHASE_END;
        LD_A1(bo, 1);
        PHASE_MID; MM(a1, 4); PHASE_END;
    }

    const int crow0 = m0 + wm * 128 + g * 4;
    const int ccol = n0 + wn * 64 + fm;
#pragma unroll
    for (int mi = 0; mi < 8; mi++)
#pragma unroll
        for (int r = 0; r < 4; r++) {
            const size_t row = (size_t)(crow0 + mi * 16 + r);
            if (OUT_BF16) {
                u16* p = (u16*)Cout + row * N + ccol;
#pragma unroll
                for (int n_ = 0; n_ < 4; n_++) p[n_ * 16] = f2b(acc[mi][n_][r]);
            } else {
                float* p = (float*)Cout + row * N + ccol;
#pragma unroll
                for (int n_ = 0; n_ < 4; n_++) p[n_ * 16] = acc[mi][n_][r];
            }
        }
#undef STG_A
#undef STG_B
#undef LD_A0
#undef LD_A1
#undef LD_B
#undef MM
#undef BARX
#undef LGKM0
#undef VM
#undef PHASE_MID
#undef PHASE_END
}

// ---------------- RoPE cos/sin table ----------------
__global__ __launch_bounds__(256) void rope_tab(const int* __restrict__ pos_ids,
                                                float2* __restrict__ tab) {
    const int idx = blockIdx.x * 256 + threadIdx.x;   // over B*SEQ*64
    const int bs = idx >> 6, i = idx & 63;
    const float invf = __expf((float)i * -0.14391156831212787f);
    const float ang = (float)pos_ids[bs] * invf;
    float sn, cs;
    __sincosf(ang, &sn, &cs);
    tab[idx] = make_float2(cs, sn);
}

// ---------------- RoPE + relayout ----------------
__global__ __launch_bounds__(256) void rope_relayout(const float2* __restrict__ tab,
                                                     const u16* __restrict__ qkv,
                                                     u16* __restrict__ Qo,
                                                     u16* __restrict__ Ko,
                                                     u16* __restrict__ VTo) {
    __shared__ u16 sV[64 * 256];
    const int st = blockIdx.x, h = blockIdx.y, b = blockIdx.z;
    const int t = threadIdx.x;
    const int sbase = st * 64;

    {
        const u16* vbase = qkv + (size_t)(b * SEQ + sbase) * N3 + 2 * HID + h * HDIM;
        const int dcol = (t & 31) * 8;
        const int tokoff = t >> 5;
#pragma unroll
        for (int r = 0; r < 4; r++)
#pragma unroll
            for (int s8 = 0; s8 < 8; s8++) {
                int tok = r * 16 + s8 * 2 + tokoff;
                async16(vbase + (size_t)tok * N3 + dcol, &sV[r * 4096 + s8 * 512 + t * 8]);
            }
    }

    const int tok = t & 63, part = t >> 6;
    const int s = sbase + tok;
    const int isK = part >> 1, isPass = part & 1;
    const u16* src = qkv + (size_t)(b * SEQ + s) * N3 + isK * HID + h * HDIM + isPass * 128;
    u16* dst = (isK ? Ko : Qo) + ((size_t)((b * NHD + h) * SEQ + s)) * HDIM + isPass * 128;
    if (!isPass) {
        const float2* trow = tab + ((size_t)(b * SEQ + s) << 6);
#pragma unroll
        for (int c = 0; c < 8; c++) {
            bf16x8 xa = *(const bf16x8*)(src + c * 8);
            bf16x8 xb = *(const bf16x8*)(src + 64 + c * 8);
            union { u16 h[8]; uint4 v; } o1, o2;
#pragma unroll
            for (int j = 0; j < 8; j++) {
                float2 t2 = trow[c * 8 + j];
                const float cs = t2.x, sn = t2.y;
                float x1 = (float)xa[j], x2 = (float)xb[j];
                o1.h[j] = f2b(x1 * cs - x2 * sn);
                o2.h[j] = f2b(x2 * cs + x1 * sn);
            }
            *(uint4*)(dst + c * 8)      = o1.v;
            *(uint4*)(dst + 64 + c * 8) = o2.v;
        }
    } else {
        const uint4* s4 = (const uint4*)src;
        uint4* d4 = (uint4*)dst;
#pragma unroll
        for (int c = 0; c < 16; c++) d4[c] = s4[c];
    }

    asm volatile("s_waitcnt vmcnt(0)" ::: "memory");
    __syncthreads();

    u16* vt = VTo + ((size_t)((b * NHD + h) * HDIM + t)) * SEQ + sbase;
#pragma unroll
    for (int g = 0; g < 8; g++) {
        union { u16 h[8]; uint4 v; } o;
#pragma unroll
        for (int j = 0; j < 8; j++) o.h[j] = sV[(g * 8 + j) * 256 + t];
        *(uint4*)(vt + g * 8) = o.v;
    }
}

// ---------------- flash attention (causal), swapped-operand 32x32 ----------------
// 4 waves x 32 q-rows = 128 q per block.  S^T = mfma32(K, Q): lane owns one query
// column; softmax is in-register (tree max/sum + one shfl_xor(32)).  P->bf16 via
// v_cvt_pk_bf16_f32 + 4 permlane32_swap.  PV swapped too: O^T = mfma32(V^T, P^T)
// keeps col=query => lane-local alpha-rescale and 1/l normalize.
// sK [32 key][256 d]: 16B chunk c stored at c^key (slot = c^key, conflict-free).
// sVT [256 d][32 s]: chunk c stored at c^((d>>3)&3) (bijective slots, 2 lanes/bank).
// Double-buffered staging; per-wave skip of fully-masked tiles.
// Load balance: blocks k and k+256 share a CU (breadth-first dispatch); q-tile
// map pairs heavy+light: nkt sums = 36 constant per CU.
__global__ __launch_bounds__(256, 2) void attn_fwd(const u16* __restrict__ Q,
                                                   const u16* __restrict__ K,
                                                   const u16* __restrict__ VT,
                                                   u16* __restrict__ attnO) {
    __shared__ u16 sK[2][32 * 256];
    __shared__ u16 sVT[2][32 * 256];
    const int bid = (int)blockIdx.x;
    const int qt8 = (bid < 256) ? (7 - (bid >> 6)) : ((bid - 256) >> 6);
    const int bh = bid & 63, h = bh & 15, b = bh >> 4;
    const int t = threadIdx.x, lane = t & 63, w = t >> 6;
    const int kid = lane & 31, hh = lane >> 5;
    const int qb = qt8 * 128;
    const int qg = qb + w * 32 + kid;            // this lane's query row
    const int qmaxw = qb + w * 32 + 31;
    const size_t head = ((size_t)(b * NHD + h)) * SEQ * HDIM;
    const u16* kbaseP = K + head;
    const u16* vtbase = VT + head;

    // Q fragments (B-operand): lane holds Q[qg][kk*16 + hh*8 + j]
    bf16x8 qf[16];
    {
        const u16* qrow = Q + head + (size_t)qg * HDIM + hh * 8;
#pragma unroll
        for (int kk = 0; kk < 16; kk++) qf[kk] = *(const bf16x8*)(qrow + kk * 16);
    }

    f32x16 accO[8];
#pragma unroll
    for (int dg = 0; dg < 8; dg++)
#pragma unroll
        for (int r = 0; r < 16; r++) accO[dg][r] = 0.f;
    float mrow = -1e30f, lrow = 0.f;

    const int nkt = qt8 * 4 + 4;
    const int vsw = (kid >> 3) & 3;              // VT read swizzle term

#define STAGE_KV(BUF, KB) do { \
    _Pragma("unroll") for (int r_ = 0; r_ < 4; r_++) { \
        const int key_ = r_ * 8 + (t >> 5); \
        const int ck_  = (t & 31) ^ key_; \
        async16(kbaseP + (size_t)((KB) * 32 + key_) * HDIM + ck_ * 8, \
                &sK[BUF][r_ * 2048 + t * 8]); } \
    _Pragma("unroll") for (int r_ = 0; r_ < 4; r_++) { \
        const int d_ = r_ * 64 + (t >> 2); \
        const int cv_ = (t & 3) ^ ((d_ >> 3) & 3); \
        async16(vtbase + (size_t)d_ * SEQ + (KB) * 32 + cv_ * 8, \
                &sVT[BUF][r_ * 2048 + t * 8]); } } while (0)

    STAGE_KV(0, 0);
    asm volatile("s_waitcnt vmcnt(0)" ::: "memory");
    __syncthreads();

    for (int kb = 0; kb < nkt; kb++) {
        const int cur = kb & 1;
        if (kb + 1 < nkt) STAGE_KV(cur ^ 1, kb + 1);   // overlaps with compute
        if ((kb << 5) <= qmaxw) {                      // wave-uniform skip
            // QK^T swapped: st[key][q]
            f32x16 st;
#pragma unroll
            for (int r = 0; r < 16; r++) st[r] = 0.f;
            __builtin_amdgcn_s_setprio(1);
#pragma unroll
            for (int kk = 0; kk < 16; kk++) {
                bf16x8 kf = *(const bf16x8*)&sK[cur][kid * 256 + ((((kk << 1) + hh) ^ kid) << 3)];
                st = __builtin_amdgcn_mfma_f32_32x32x16_bf16(kf, qf[kk], st, 0, 0, 0);
            }
            __builtin_amdgcn_s_setprio(0);
            // masked in-register softmax; key_r = kb*32 + (r&3)+8*(r>>2)+4*hh
            const int kb32 = kb << 5;
            float p[16];
            float mt = -1e30f;
#pragma unroll
            for (int r = 0; r < 16; r++) {
                const int kgl = kb32 + (r & 3) + 8 * (r >> 2) + 4 * hh;
                p[r] = (kgl <= qg) ? st[r] * 0.0625f : -1e30f;
                mt = fmaxf(mt, p[r]);
            }
            mt = fmaxf(mt, __shfl_xor(mt, 32, 64));
            const float mold = mrow;
            const float mn = fmaxf(mold, mt);
            mrow = mn;
            float rs = 0.f;
#pragma unroll
            for (int r = 0; r < 16; r++) { p[r] = __expf(p[r] - mn); rs += p[r]; }
            rs += __shfl_xor(rs, 32, 64);
            const float alpha = __expf(mold - mn);
            lrow = lrow * alpha + rs;
            if (__any(mn > mold)) {                    // exact skip when alpha==1
#pragma unroll
                for (int dg = 0; dg < 8; dg++)
#pragma unroll
                    for (int r = 0; r < 16; r++) accO[dg][r] *= alpha;
            }
            // pack P -> P^T B-fragments: cvt_pk + 4 permlane32_swap
            unsigned pw[8];
#pragma unroll
            for (int i = 0; i < 8; i++) pw[i] = cvt_pk_bf16(p[2 * i], p[2 * i + 1]);
            { auto r2 = __builtin_amdgcn_permlane32_swap(pw[0], pw[2], false, false); pw[0] = r2[0]; pw[2] = r2[1]; }
            { auto r2 = __builtin_amdgcn_permlane32_swap(pw[1], pw[3], false, false); pw[1] = r2[0]; pw[3] = r2[1]; }
            { auto r2 = __builtin_amdgcn_permlane32_swap(pw[4], pw[6], false, false); pw[4] = r2[0]; pw[6] = r2[1]; }
            { auto r2 = __builtin_amdgcn_permlane32_swap(pw[5], pw[7], false, false); pw[5] = r2[0]; pw[7] = r2[1]; }
            union { uint4 q; bf16x8 v; } f0, f1;
            f0.q = make_uint4(pw[0], pw[1], pw[2], pw[3]);
            f1.q = make_uint4(pw[4], pw[5], pw[6], pw[7]);
            // PV swapped: accO[dg] = V^T x P^T (+accO); col = query
            __builtin_amdgcn_s_setprio(1);
#pragma unroll
            for (int dg = 0; dg < 8; dg++) {
                bf16x8 vf = *(const bf16x8*)&sVT[cur][(dg * 32 + kid) * 32 + ((hh ^ vsw) << 3)];
                accO[dg] = __builtin_amdgcn_mfma_f32_32x32x16_bf16(vf, f0.v, accO[dg], 0, 0, 0);
            }
#pragma unroll
            for (int dg = 0; dg < 8; dg++) {
                bf16x8 vf = *(const bf16x8*)&sVT[cur][(dg * 32 + kid) * 32 + (((2 + hh) ^ vsw) << 3)];
                accO[dg] = __builtin_amdgcn_mfma_f32_32x32x16_bf16(vf, f1.v, accO[dg], 0, 0, 0);
            }
            __builtin_amdgcn_s_setprio(0);
        }
        asm volatile("s_waitcnt vmcnt(0)" ::: "memory");  // next-tile loads landed
        __syncthreads();                                  // protect buffer reuse
    }
#undef STAGE_KV
    // write: lane q holds O[qg][dg*32 + 8*rq + 4*hh + i]
    const float inv = 1.0f / lrow;
    u16* orow = attnO + (size_t)(b * SEQ + qg) * HID + h * HDIM;
#pragma unroll
    for (int dg = 0; dg < 8; dg++)
#pragma unroll
        for (int rq = 0; rq < 4; rq++) {
            union { u16 h4[4]; unsigned long long v; } o;
#pragma unroll
            for (int i = 0; i < 4; i++) o.h4[i] = f2b(accO[dg][rq * 4 + i] * inv);
            *(unsigned long long*)(orow + dg * 32 + rq * 8 + hh * 4) = o.v;
        }
}

// ---------------- launch ----------------
extern "C" void kernel_launch(void* const* d_in, const int* in_sizes, int n_in,
                              void* d_out, int out_size, void* d_ws, size_t ws_size,
                              hipStream_t stream) {
    (void)in_sizes; (void)n_in; (void)out_size; (void)ws_size;
    const int*   pos    = (const int*)d_in[0];
    const float* hidden = (const float*)d_in[1];
    const float* wqkv   = (const float*)d_in[2];
    const float* wout   = (const float*)d_in[3];
    float* out = (float*)d_out;
    char* ws = (char*)d_ws;

    u16* hiddenB = (u16*)ws;                              //  33,554,432 B
    u16* wqkvT   = (u16*)(ws + (size_t)33554432);         // 100,663,296 B
    u16* woutT   = (u16*)(ws + (size_t)134217728);        //  33,554,432 B
    u16* qkv     = (u16*)(ws + (size_t)167772160);        // 100,663,296 B
    u16* Qb    = wqkvT;                 // after GEMM1, wqkvT is dead
    u16* Kb    = wqkvT + 16777216;
    u16* VTb   = wqkvT + 33554432;
    u16* attnB = qkv;                   // after rope, qkv is dead
    float2* tabF = (float2*)ws;         // after GEMM1, hiddenB is dead (2 MB table)

    cast_bf16<<<dim3(TOK * HID / 8 / 256), 256, 0, stream>>>(
        (const float4*)hidden, (uint4*)hiddenB, TOK * HID / 8);
    tcast<<<dim3(N3 / 64, HID / 64), 256, 0, stream>>>(wqkv, wqkvT, HID, N3);
    tcast<<<dim3(HID / 64, HID / 64), 256, 0, stream>>>(wout, woutT, HID, HID);
    gemm256<true><<<dim3((TOK / 256) * (N3 / 256)), 512, 0, stream>>>(
        hiddenB, wqkvT, qkv, TOK, N3, HID);
    rope_tab<<<dim3(BB * SEQ * 64 / 256), 256, 0, stream>>>(pos, tabF);
    rope_relayout<<<dim3(SEQ / 64, NHD, BB), 256, 0, stream>>>(tabF, qkv, Qb, Kb, VTb);
    attn_fwd<<<dim3(512), 256, 0, stream>>>(Qb, Kb, VTb, attnB);
    gemm256<false><<<dim3((TOK / 256) * (HID / 256)), 512, 0, stream>>>(
        attnB, woutT, out, TOK, HID, HID);
}

// Round 5
// 1004.437 us; speedup vs baseline: 1.3908x; 1.0101x over previous
//
#include <hip/hip_runtime.h>
#include <cstdint>

#define HID  4096
#define NHD  16
#define HDIM 256
#define SEQ  1024
#define BB   4
#define N3   12288
#define TOK  4096

typedef unsigned short u16;
typedef __bf16 bf16x8 __attribute__((ext_vector_type(8)));
typedef float  f32x4  __attribute__((ext_vector_type(4)));
typedef float  f32x16 __attribute__((ext_vector_type(16)));

__device__ __forceinline__ u16 f2b(float f) {
    unsigned u = __builtin_bit_cast(unsigned, f);
    u += 0x7fffu + ((u >> 16) & 1u);          // RNE
    return (u16)(u >> 16);
}
__device__ __forceinline__ float b2f(u16 v) {
    unsigned u = ((unsigned)v) << 16;
    return __builtin_bit_cast(float, u);
}
__device__ __forceinline__ unsigned cvt_pk_bf16(float lo, float hi) {
    unsigned r;
    asm("v_cvt_pk_bf16_f32 %0, %1, %2" : "=v"(r) : "v"(lo), "v"(hi));
    return r;
}

typedef __attribute__((address_space(3))) unsigned       lds_u32;
typedef const __attribute__((address_space(1))) unsigned glb_u32;
__device__ __forceinline__ void async16(const void* g, void* l) {
    __builtin_amdgcn_global_load_lds((glb_u32*)g, (lds_u32*)l, 16, 0, 0);
}

// ---------------- cast fp32 -> bf16 (row-major) ----------------
__global__ __launch_bounds__(256) void cast_bf16(const float4* __restrict__ in,
                                                 uint4* __restrict__ out, int n8) {
    int i = blockIdx.x * 256 + threadIdx.x;
    if (i >= n8) return;
    float4 a = in[2 * i], b = in[2 * i + 1];
    union { u16 h[8]; uint4 v; } o;
    o.h[0] = f2b(a.x); o.h[1] = f2b(a.y); o.h[2] = f2b(a.z); o.h[3] = f2b(a.w);
    o.h[4] = f2b(b.x); o.h[5] = f2b(b.y); o.h[6] = f2b(b.z); o.h[7] = f2b(b.w);
    out[i] = o.v;
}

// ---------------- transpose-cast: in[R][C] fp32 -> out[C][R] bf16 ----------------
__global__ __launch_bounds__(256) void tcast(const float* __restrict__ in,
                                             u16* __restrict__ out, int R, int C) {
    __shared__ u16 sT[64 * 80];
    const int c0 = blockIdx.x * 64, r0 = blockIdx.y * 64;
    const int t = threadIdx.x;
    const int rr = t >> 4, cc = (t & 15) * 4;
    for (int rnd = 0; rnd < 4; rnd++) {
        int r = rnd * 16 + rr;
        float4 v = *(const float4*)(in + (size_t)(r0 + r) * C + c0 + cc);
        sT[(cc + 0) * 80 + r] = f2b(v.x);
        sT[(cc + 1) * 80 + r] = f2b(v.y);
        sT[(cc + 2) * 80 + r] = f2b(v.z);
        sT[(cc + 3) * 80 + r] = f2b(v.w);
    }
    __syncthreads();
    const int orow = t >> 2, oc = (t & 3) * 16;
    u16* dst = out + (size_t)(c0 + orow) * R + r0 + oc;
    *(uint4*)dst       = *(uint4*)&sT[orow * 80 + oc];
    *(uint4*)(dst + 8) = *(uint4*)&sT[orow * 80 + oc + 8];
}

// ---------------- bf16 GEMM: C[M][N] = A[M][K] * Bt[N][K]^T ----------------
// 256x256 tile, 512 threads = 8 waves (2M x 4N), 16x16x32 MFMA.
// LDS re-cut as a 4-SLICE RING (BK=32 per slice: A[256][32] + B[256][32] = 32 KiB)
// = 128 KiB total.  Staging for K-step ks+3 issued during step ks -> prefetch
// distance 3 K-steps (~1200 cy), one vmcnt(8) per K-step (12 outstanding,
// drains the 4 loads of step ks+1, issued 6 phases earlier).  Chunk swizzle
// swz(row) = (row&3)^((row>>2)&2) on the global source side (conflict-free
// ds_read_b128, verified conflicts=0).  2 phases per K-step, each
// {ds_read 8|4 frags, stage A|B slice, barrier, lgkmcnt(0), setprio(1),
//  16 MFMA, setprio(0), barrier}.  Requires K % 128 == 0 (K = 4096 here).
template <bool OUT_BF16>
__global__ __launch_bounds__(512, 2) void gemm256(const u16* __restrict__ A,
                                                  const u16* __restrict__ Bt,
                                                  void* __restrict__ Cout,
                                                  int M, int N, int K) {
    __shared__ alignas(16) u16 lds[65536];   // 4 x (A 8192 + B 8192) u16
    const int t = threadIdx.x;
    const int lane = t & 63, w = t >> 6;
    const int wm = w >> 2, wn = w & 3;
    const int fm = lane & 15, g = lane >> 4;

    // XCD-aware block swizzle (grid is 1-D, nwg % 8 == 0 for our shapes)
    const int nwg = (int)gridDim.x;
    const int cpx = nwg >> 3;
    const int swz = (((int)blockIdx.x) & 7) * cpx + (((int)blockIdx.x) >> 3);
    const int gm = M >> 8;
    const int mblk = swz % gm, nblk = swz / gm;
    const int m0 = mblk << 8, n0 = nblk << 8;

    // staging source: row = t>>2 (+128 for 2nd issue), 16B chunk pre-swizzled
    const int srow = t >> 2;
    const int schk = ((t & 3) ^ (srow & 3) ^ ((srow >> 2) & 2)) * 8;
    const u16* gA = A  + (size_t)(m0 + srow) * K + schk;
    const u16* gB = Bt + (size_t)(n0 + srow) * K + schk;
    const size_t hstep = (size_t)128 * K;
    const int ldst = t * 8;

    // fragment read offsets (elems): slice is [256][32], chunk = g ^ swz(row)
    const int cxor = (g ^ (fm & 3) ^ ((fm >> 2) & 2)) * 8;
    const int aoff = (wm * 128 + fm) * 32 + cxor;         // A at slice+0
    const int boff = 8192 + (wn * 64 + fm) * 32 + cxor;   // B at slice+8192

    f32x4 acc[8][4];
#pragma unroll
    for (int i = 0; i < 8; i++)
#pragma unroll
        for (int j = 0; j < 4; j++) acc[i][j] = f32x4{0.f, 0.f, 0.f, 0.f};

    bf16x8 a0[4], a1[4], bfr[4];

#define STG_As(S, KE) do { const u16* s_ = gA + (KE); \
    async16(s_,         &lds[(S) * 16384 + ldst]); \
    async16(s_ + hstep, &lds[(S) * 16384 + 4096 + ldst]); } while (0)
#define STG_Bs(S, KE) do { const u16* s_ = gB + (KE); \
    async16(s_,         &lds[(S) * 16384 + 8192 + ldst]); \
    async16(s_ + hstep, &lds[(S) * 16384 + 12288 + ldst]); } while (0)
#define LD_A0s(S) { _Pragma("unroll") for (int m_ = 0; m_ < 4; m_++) \
    a0[m_] = *(const bf16x8*)&lds[(S) * 16384 + aoff + m_ * 512]; }
#define LD_A1s(S) { _Pragma("unroll") for (int m_ = 0; m_ < 4; m_++) \
    a1[m_] = *(const bf16x8*)&lds[(S) * 16384 + 2048 + aoff + m_ * 512]; }
#define LD_Bs(S)  { _Pragma("unroll") for (int n_ = 0; n_ < 4; n_++) \
    bfr[n_] = *(const bf16x8*)&lds[(S) * 16384 + boff + n_ * 512]; }
#define MM(AR, MO) { _Pragma("unroll") for (int m_ = 0; m_ < 4; m_++) \
    _Pragma("unroll") for (int n_ = 0; n_ < 4; n_++) \
    acc[(MO) + m_][n_] = __builtin_amdgcn_mfma_f32_16x16x32_bf16(AR[m_], bfr[n_], acc[(MO) + m_][n_], 0, 0, 0); }
#define BARX __builtin_amdgcn_s_barrier()
#define VM(N_) asm volatile("s_waitcnt vmcnt(" #N_ ")" ::: "memory")
#define PHASE_MID BARX; asm volatile("s_waitcnt lgkmcnt(0)" ::: "memory"); \
    __builtin_amdgcn_s_setprio(1)
#define PHASE_END __builtin_amdgcn_s_setprio(0); BARX

    // prologue: stage K-steps 0,1,2 into slices 0,1,2; publish slice 0
    STG_As(0, 0);  STG_Bs(0, 0);
    STG_As(1, 32); STG_Bs(1, 32);
    STG_As(2, 64); STG_Bs(2, 64);
    VM(8); BARX;

    const int nko = (K >> 7) - 1;   // groups of 4 K-steps; last group peeled
#pragma unroll 1
    for (int o = 0; o < nko; o++) {
        const int kOff = o << 7;    // elem offset of this group's first K-step
#pragma unroll
        for (int j = 0; j < 4; j++) {           // K-step ks = 4o+j, slice j
            // P0: A frags m0-3 + B frags | stage A slice for ks+3
            LD_A0s(j); LD_Bs(j);
            STG_As((j + 3) & 3, kOff + (j + 3) * 32);
            PHASE_MID; MM(a0, 0); PHASE_END;
            // P1: A frags m4-7 | stage B slice for ks+3 | publish ks+1
            LD_A1s(j);
            STG_Bs((j + 3) & 3, kOff + (j + 3) * 32);
            VM(8);
            PHASE_MID; MM(a1, 4); PHASE_END;
        }
    }
    {   // tail: K-steps nks-4 .. nks-1 (slices 0..3); drain 8 -> 4 -> 0
        const int kOff = nko << 7;
        // ks = nks-4 (slice 0): still stages the final K-step (slice 3)
        LD_A0s(0); LD_Bs(0);
        STG_As(3, kOff + 96);
        PHASE_MID; MM(a0, 0); PHASE_END;
        LD_A1s(0);
        STG_Bs(3, kOff + 96);
        VM(8);
        PHASE_MID; MM(a1, 4); PHASE_END;
        // ks = nks-3 (slice 1)
        LD_A0s(1); LD_Bs(1);
        PHASE_MID; MM(a0, 0); PHASE_END;
        LD_A1s(1);
        VM(4);
        PHASE_MID; MM(a1, 4); PHASE_END;
        // ks = nks-2 (slice 2)
        LD_A0s(2); LD_Bs(2);
        PHASE_MID; MM(a0, 0); PHASE_END;
        LD_A1s(2);
        VM(0);
        PHASE_MID; MM(a1, 4); PHASE_END;
        // ks = nks-1 (slice 3): nothing outstanding
        LD_A0s(3); LD_Bs(3);
        PHASE_MID; MM(a0, 0); PHASE_END;
        LD_A1s(3);
        PHASE_MID; MM(a1, 4);
        __builtin_amdgcn_s_setprio(0);
    }

    // C/D layout (16x16): col = lane&15, row = (lane>>4)*4 + reg
    const int crow0 = m0 + wm * 128 + g * 4;
    const int ccol = n0 + wn * 64 + fm;
#pragma unroll
    for (int mi = 0; mi < 8; mi++)
#pragma unroll
        for (int r = 0; r < 4; r++) {
            const size_t row = (size_t)(crow0 + mi * 16 + r);
            if (OUT_BF16) {
                u16* p = (u16*)Cout + row * N + ccol;
#pragma unroll
                for (int n_ = 0; n_ < 4; n_++) p[n_ * 16] = f2b(acc[mi][n_][r]);
            } else {
                float* p = (float*)Cout + row * N + ccol;
#pragma unroll
                for (int n_ = 0; n_ < 4; n_++) p[n_ * 16] = acc[mi][n_][r];
            }
        }
#undef STG_As
#undef STG_Bs
#undef LD_A0s
#undef LD_A1s
#undef LD_Bs
#undef MM
#undef BARX
#undef VM
#undef PHASE_MID
#undef PHASE_END
}

// ---------------- RoPE cos/sin table ----------------
__global__ __launch_bounds__(256) void rope_tab(const int* __restrict__ pos_ids,
                                                float2* __restrict__ tab) {
    const int idx = blockIdx.x * 256 + threadIdx.x;   // over B*SEQ*64
    const int bs = idx >> 6, i = idx & 63;
    const float invf = __expf((float)i * -0.14391156831212787f);
    const float ang = (float)pos_ids[bs] * invf;
    float sn, cs;
    __sincosf(ang, &sn, &cs);
    tab[idx] = make_float2(cs, sn);
}

// ---------------- RoPE + relayout ----------------
__global__ __launch_bounds__(256) void rope_relayout(const float2* __restrict__ tab,
                                                     const u16* __restrict__ qkv,
                                                     u16* __restrict__ Qo,
                                                     u16* __restrict__ Ko,
                                                     u16* __restrict__ VTo) {
    __shared__ u16 sV[64 * 256];
    const int st = blockIdx.x, h = blockIdx.y, b = blockIdx.z;
    const int t = threadIdx.x;
    const int sbase = st * 64;

    {
        const u16* vbase = qkv + (size_t)(b * SEQ + sbase) * N3 + 2 * HID + h * HDIM;
        const int dcol = (t & 31) * 8;
        const int tokoff = t >> 5;
#pragma unroll
        for (int r = 0; r < 4; r++)
#pragma unroll
            for (int s8 = 0; s8 < 8; s8++) {
                int tok = r * 16 + s8 * 2 + tokoff;
                async16(vbase + (size_t)tok * N3 + dcol, &sV[r * 4096 + s8 * 512 + t * 8]);
            }
    }

    const int tok = t & 63, part = t >> 6;
    const int s = sbase + tok;
    const int isK = part >> 1, isPass = part & 1;
    const u16* src = qkv + (size_t)(b * SEQ + s) * N3 + isK * HID + h * HDIM + isPass * 128;
    u16* dst = (isK ? Ko : Qo) + ((size_t)((b * NHD + h) * SEQ + s)) * HDIM + isPass * 128;
    if (!isPass) {
        const float2* trow = tab + ((size_t)(b * SEQ + s) << 6);
#pragma unroll
        for (int c = 0; c < 8; c++) {
            bf16x8 xa = *(const bf16x8*)(src + c * 8);
            bf16x8 xb = *(const bf16x8*)(src + 64 + c * 8);
            union { u16 h[8]; uint4 v; } o1, o2;
#pragma unroll
            for (int j = 0; j < 8; j++) {
                float2 t2 = trow[c * 8 + j];
                const float cs = t2.x, sn = t2.y;
                float x1 = (float)xa[j], x2 = (float)xb[j];
                o1.h[j] = f2b(x1 * cs - x2 * sn);
                o2.h[j] = f2b(x2 * cs + x1 * sn);
            }
            *(uint4*)(dst + c * 8)      = o1.v;
            *(uint4*)(dst + 64 + c * 8) = o2.v;
        }
    } else {
        const uint4* s4 = (const uint4*)src;
        uint4* d4 = (uint4*)dst;
#pragma unroll
        for (int c = 0; c < 16; c++) d4[c] = s4[c];
    }

    asm volatile("s_waitcnt vmcnt(0)" ::: "memory");
    __syncthreads();

    u16* vt = VTo + ((size_t)((b * NHD + h) * HDIM + t)) * SEQ + sbase;
#pragma unroll
    for (int g = 0; g < 8; g++) {
        union { u16 h[8]; uint4 v; } o;
#pragma unroll
        for (int j = 0; j < 8; j++) o.h[j] = sV[(g * 8 + j) * 256 + t];
        *(uint4*)(vt + g * 8) = o.v;
    }
}

// ---------------- flash attention (causal), swapped-operand 32x32 ----------------
// (unchanged from round 4 -- control group)
__global__ __launch_bounds__(256, 2) void attn_fwd(const u16* __restrict__ Q,
                                                   const u16* __restrict__ K,
                                                   const u16* __restrict__ VT,
                                                   u16* __restrict__ attnO) {
    __shared__ u16 sK[2][32 * 256];
    __shared__ u16 sVT[2][32 * 256];
    const int bid = (int)blockIdx.x;
    const int qt8 = (bid < 256) ? (7 - (bid >> 6)) : ((bid - 256) >> 6);
    const int bh = bid & 63, h = bh & 15, b = bh >> 4;
    const int t = threadIdx.x, lane = t & 63, w = t >> 6;
    const int kid = lane & 31, hh = lane >> 5;
    const int qb = qt8 * 128;
    const int qg = qb + w * 32 + kid;            // this lane's query row
    const int qmaxw = qb + w * 32 + 31;
    const size_t head = ((size_t)(b * NHD + h)) * SEQ * HDIM;
    const u16* kbaseP = K + head;
    const u16* vtbase = VT + head;

    bf16x8 qf[16];
    {
        const u16* qrow = Q + head + (size_t)qg * HDIM + hh * 8;
#pragma unroll
        for (int kk = 0; kk < 16; kk++) qf[kk] = *(const bf16x8*)(qrow + kk * 16);
    }

    f32x16 accO[8];
#pragma unroll
    for (int dg = 0; dg < 8; dg++)
#pragma unroll
        for (int r = 0; r < 16; r++) accO[dg][r] = 0.f;
    float mrow = -1e30f, lrow = 0.f;

    const int nkt = qt8 * 4 + 4;
    const int vsw = (kid >> 3) & 3;              // VT read swizzle term

#define STAGE_KV(BUF, KB) do { \
    _Pragma("unroll") for (int r_ = 0; r_ < 4; r_++) { \
        const int key_ = r_ * 8 + (t >> 5); \
        const int ck_  = (t & 31) ^ key_; \
        async16(kbaseP + (size_t)((KB) * 32 + key_) * HDIM + ck_ * 8, \
                &sK[BUF][r_ * 2048 + t * 8]); } \
    _Pragma("unroll") for (int r_ = 0; r_ < 4; r_++) { \
        const int d_ = r_ * 64 + (t >> 2); \
        const int cv_ = (t & 3) ^ ((d_ >> 3) & 3); \
        async16(vtbase + (size_t)d_ * SEQ + (KB) * 32 + cv_ * 8, \
                &sVT[BUF][r_ * 2048 + t * 8]); } } while (0)

    STAGE_KV(0, 0);
    asm volatile("s_waitcnt vmcnt(0)" ::: "memory");
    __syncthreads();

    for (int kb = 0; kb < nkt; kb++) {
        const int cur = kb & 1;
        if (kb + 1 < nkt) STAGE_KV(cur ^ 1, kb + 1);   // overlaps with compute
        if ((kb << 5) <= qmaxw) {                      // wave-uniform skip
            f32x16 st;
#pragma unroll
            for (int r = 0; r < 16; r++) st[r] = 0.f;
            __builtin_amdgcn_s_setprio(1);
#pragma unroll
            for (int kk = 0; kk < 16; kk++) {
                bf16x8 kf = *(const bf16x8*)&sK[cur][kid * 256 + ((((kk << 1) + hh) ^ kid) << 3)];
                st = __builtin_amdgcn_mfma_f32_32x32x16_bf16(kf, qf[kk], st, 0, 0, 0);
            }
            __builtin_amdgcn_s_setprio(0);
            const int kb32 = kb << 5;
            float p[16];
            float mt = -1e30f;
#pragma unroll
            for (int r = 0; r < 16; r++) {
                const int kgl = kb32 + (r & 3) + 8 * (r >> 2) + 4 * hh;
                p[r] = (kgl <= qg) ? st[r] * 0.0625f : -1e30f;
                mt = fmaxf(mt, p[r]);
            }
            mt = fmaxf(mt, __shfl_xor(mt, 32, 64));
            const float mold = mrow;
            const float mn = fmaxf(mold, mt);
            mrow = mn;
            float rs = 0.f;
#pragma unroll
            for (int r = 0; r < 16; r++) { p[r] = __expf(p[r] - mn); rs += p[r]; }
            rs += __shfl_xor(rs, 32, 64);
            const float alpha = __expf(mold - mn);
            lrow = lrow * alpha + rs;
            if (__any(mn > mold)) {                    // exact skip when alpha==1
#pragma unroll
                for (int dg = 0; dg < 8; dg++)
#pragma unroll
                    for (int r = 0; r < 16; r++) accO[dg][r] *= alpha;
            }
            unsigned pw[8];
#pragma unroll
            for (int i = 0; i < 8; i++) pw[i] = cvt_pk_bf16(p[2 * i], p[2 * i + 1]);
            { auto r2 = __builtin_amdgcn_permlane32_swap(pw[0], pw[2], false, false); pw[0] = r2[0]; pw[2] = r2[1]; }
            { auto r2 = __builtin_amdgcn_permlane32_swap(pw[1], pw[3], false, false); pw[1] = r2[0]; pw[3] = r2[1]; }
            { auto r2 = __builtin_amdgcn_permlane32_swap(pw[4], pw[6], false, false); pw[4] = r2[0]; pw[6] = r2[1]; }
            { auto r2 = __builtin_amdgcn_permlane32_swap(pw[5], pw[7], false, false); pw[5] = r2[0]; pw[7] = r2[1]; }
            union { uint4 q; bf16x8 v; } f0, f1;
            f0.q = make_uint4(pw[0], pw[1], pw[2], pw[3]);
            f1.q = make_uint4(pw[4], pw[5], pw[6], pw[7]);
            __builtin_amdgcn_s_setprio(1);
#pragma unroll
            for (int dg = 0; dg < 8; dg++) {
                bf16x8 vf = *(const bf16x8*)&sVT[cur][(dg * 32 + kid) * 32 + ((hh ^ vsw) << 3)];
                accO[dg] = __builtin_amdgcn_mfma_f32_32x32x16_bf16(vf, f0.v, accO[dg], 0, 0, 0);
            }
#pragma unroll
            for (int dg = 0; dg < 8; dg++) {
                bf16x8 vf = *(const bf16x8*)&sVT[cur][(dg * 32 + kid) * 32 + (((2 + hh) ^ vsw) << 3)];
                accO[dg] = __builtin_amdgcn_mfma_f32_32x32x16_bf16(vf, f1.v, accO[dg], 0, 0, 0);
            }
            __builtin_amdgcn_s_setprio(0);
        }
        asm volatile("s_waitcnt vmcnt(0)" ::: "memory");  // next-tile loads landed
        __syncthreads();                                  // protect buffer reuse
    }
#undef STAGE_KV
    const float inv = 1.0f / lrow;
    u16* orow = attnO + (size_t)(b * SEQ + qg) * HID + h * HDIM;
#pragma unroll
    for (int dg = 0; dg < 8; dg++)
#pragma unroll
        for (int rq = 0; rq < 4; rq++) {
            union { u16 h4[4]; unsigned long long v; } o;
#pragma unroll
            for (int i = 0; i < 4; i++) o.h4[i] = f2b(accO[dg][rq * 4 + i] * inv);
            *(unsigned long long*)(orow + dg * 32 + rq * 8 + hh * 4) = o.v;
        }
}

// ---------------- launch ----------------
extern "C" void kernel_launch(void* const* d_in, const int* in_sizes, int n_in,
                              void* d_out, int out_size, void* d_ws, size_t ws_size,
                              hipStream_t stream) {
    (void)in_sizes; (void)n_in; (void)out_size; (void)ws_size;
    const int*   pos    = (const int*)d_in[0];
    const float* hidden = (const float*)d_in[1];
    const float* wqkv   = (const float*)d_in[2];
    const float* wout   = (const float*)d_in[3];
    float* out = (float*)d_out;
    char* ws = (char*)d_ws;

    u16* hiddenB = (u16*)ws;                              //  33,554,432 B
    u16* wqkvT   = (u16*)(ws + (size_t)33554432);         // 100,663,296 B
    u16* woutT   = (u16*)(ws + (size_t)134217728);        //  33,554,432 B
    u16* qkv     = (u16*)(ws + (size_t)167772160);        // 100,663,296 B
    u16* Qb    = wqkvT;                 // after GEMM1, wqkvT is dead
    u16* Kb    = wqkvT + 16777216;
    u16* VTb   = wqkvT + 33554432;
    u16* attnB = qkv;                   // after rope, qkv is dead
    float2* tabF = (float2*)ws;         // after GEMM1, hiddenB is dead (2 MB table)

    cast_bf16<<<dim3(TOK * HID / 8 / 256), 256, 0, stream>>>(
        (const float4*)hidden, (uint4*)hiddenB, TOK * HID / 8);
    tcast<<<dim3(N3 / 64, HID / 64), 256, 0, stream>>>(wqkv, wqkvT, HID, N3);
    tcast<<<dim3(HID / 64, HID / 64), 256, 0, stream>>>(wout, woutT, HID, HID);
    gemm256<true><<<dim3((TOK / 256) * (N3 / 256)), 512, 0, stream>>>(
        hiddenB, wqkvT, qkv, TOK, N3, HID);
    rope_tab<<<dim3(BB * SEQ * 64 / 256), 256, 0, stream>>>(pos, tabF);
    rope_relayout<<<dim3(SEQ / 64, NHD, BB), 256, 0, stream>>>(tabF, qkv, Qb, Kb, VTb);
    attn_fwd<<<dim3(512), 256, 0, stream>>>(Qb, Kb, VTb, attnB);
    gemm256<false><<<dim3((TOK / 256) * (HID / 256)), 512, 0, stream>>>(
        attnB, woutT, out, TOK, HID, HID);
}